// Round 1
// baseline (1001.758 us; speedup 1.0000x reference)
//
#include <hip/hip_runtime.h>

constexpr int kNUser = 100000;
constexpr int kNItem = 50000;
constexpr int kN     = 150000;
constexpr int kEmb   = 64;
constexpr int kFeat  = 384;
constexpr int kNnz   = 2400000;
constexpr float kEps = 1e-8f;

constexpr int kChunk = 1024;                       // elements per scan block
constexpr int kNB    = (kN + kChunk - 1) / kChunk; // 147 scan blocks

// ================= shared init kernels =================

__global__ void prompt_sum_k(const float* __restrict__ p, float* __restrict__ out) {
    int d = threadIdx.x;  // 64 threads
    float s = 0.f;
#pragma unroll
    for (int i = 0; i < 8; ++i) s += p[i * kEmb + d];
    out[d] = s;
}

__global__ void user_ego_k(const float* __restrict__ uf, const float* __restrict__ ps,
                           float* __restrict__ ego) {
    int i = blockIdx.x * blockDim.x + threadIdx.x;
    if (i >= kNUser * kEmb) return;
    ego[i] = uf[i] + ps[i & 63];
}

// ---- item MLP: block = 64 rows; A staged through LDS (coalesced), compute
// reads A as wave-uniform ds_read_b128 broadcasts. R5 post-mortem: the
// 1536 wave-uniform global float4 loads/wave were VMEM-issue/latency bound
// (259us @ VALUBusy 17%). LDS staging cuts per-wave VMEM ~1920 -> ~400.
constexpr int kRW      = 16;   // rows per wave
constexpr int kRowsBlk = 64;   // rows per block (4 waves)
constexpr int kKc      = 32;   // K-chunk

__global__ __launch_bounds__(256, 2)
void item_ego_k(const float* __restrict__ itf, const float* __restrict__ w,
                const float* __restrict__ b, float* __restrict__ ego) {
    __shared__ float lds_a[kRowsBlk * kKc];  // 8 KB
    int t      = threadIdx.x;
    int wid    = t >> 6;
    int lane   = t & 63;
    int blk_r0 = blockIdx.x * kRowsBlk;

    float acc[kRW];
#pragma unroll
    for (int r = 0; r < kRW; ++r) acc[r] = 0.f;

    int srow = t >> 3;             // 0..31
    int scol = (t & 7) * 4;        // 0,4,..,28

    for (int kc = 0; kc < kFeat; kc += kKc) {
        __syncthreads();  // previous-chunk LDS reads done
        // ---- stage A tile: 64 rows x 32 k = 2048 floats, 2 float4/thread ----
        {
            const float4 z = make_float4(0.f, 0.f, 0.f, 0.f);
            int gr0 = blk_r0 + srow;
            int gr1 = gr0 + 32;
            float4 v0 = (gr0 < kNItem)
                ? *(const float4*)(itf + (size_t)gr0 * kFeat + kc + scol) : z;
            float4 v1 = (gr1 < kNItem)
                ? *(const float4*)(itf + (size_t)gr1 * kFeat + kc + scol) : z;
            *(float4*)(lds_a + srow * kKc + scol)        = v0;
            *(float4*)(lds_a + (srow + 32) * kKc + scol) = v1;
        }
        // ---- W chunk into registers (coalesced, independent of LDS) ----
        float wreg[kKc];
#pragma unroll
        for (int k = 0; k < kKc; ++k) wreg[k] = w[(kc + k) * kEmb + lane];
        __syncthreads();  // staging visible
        // ---- compute: wave-uniform LDS broadcasts ----
#pragma unroll
        for (int r = 0; r < kRW; ++r) {
            const float4* av = (const float4*)(lds_a + (wid * kRW + r) * kKc);
#pragma unroll
            for (int q = 0; q < 8; ++q) {
                float4 a = av[q];
                acc[r] = fmaf(a.x, wreg[q * 4 + 0], acc[r]);
                acc[r] = fmaf(a.y, wreg[q * 4 + 1], acc[r]);
                acc[r] = fmaf(a.z, wreg[q * 4 + 2], acc[r]);
                acc[r] = fmaf(a.w, wreg[q * 4 + 3], acc[r]);
            }
        }
    }
    float bv = b[lane];
#pragma unroll
    for (int r = 0; r < kRW; ++r) {
        int row = blk_r0 + wid * kRW + r;
        if (row < kNItem)
            ego[(size_t)(kNUser + row) * kEmb + lane] = tanhf(acc[r] + bv);
    }
}

// nrm + acc init (CSR path: layer 0 reads ego directly, no x copy needed)
__global__ void norm_init_csr_k(const float* __restrict__ ego, float* __restrict__ nrm,
                                float* __restrict__ acc) {
    int wid  = threadIdx.x >> 6;
    int lane = threadIdx.x & 63;
    int row  = blockIdx.x * 4 + wid;
    if (row >= kN) return;
    size_t idx = (size_t)row * kEmb + lane;
    float e = ego[idx];
    acc[idx] = e;
    float s = e * e;
#pragma unroll
    for (int o = 32; o >= 1; o >>= 1) s += __shfl_xor(s, o, 64);
    if (lane == 0) nrm[row] = sqrtf(s);
}

// ================= CSR build =================

__global__ void hist_k(const int* __restrict__ rows, int* __restrict__ cnt) {
    int e = blockIdx.x * blockDim.x + threadIdx.x;
    if (e < kNnz) atomicAdd(&cnt[rows[e]], 1);
}

__global__ void scan1_k(const int* __restrict__ cnt, int* __restrict__ excl_out,
                        int* __restrict__ blk_sum) {
    __shared__ int sd[256];
    int b = blockIdx.x, t = threadIdx.x;
    int base = b * kChunk + t * 4;
    int c0 = (base + 0 < kN) ? cnt[base + 0] : 0;
    int c1 = (base + 1 < kN) ? cnt[base + 1] : 0;
    int c2 = (base + 2 < kN) ? cnt[base + 2] : 0;
    int c3 = (base + 3 < kN) ? cnt[base + 3] : 0;
    int tsum = c0 + c1 + c2 + c3;
    sd[t] = tsum;
    __syncthreads();
#pragma unroll
    for (int off = 1; off < 256; off <<= 1) {
        int v = (t >= off) ? sd[t - off] : 0;
        __syncthreads();
        sd[t] += v;
        __syncthreads();
    }
    int excl = sd[t] - tsum;
    if (t == 255) blk_sum[b] = sd[255];
    int run = excl;
    if (base + 0 < kN) { excl_out[base + 0] = run; run += c0; }
    if (base + 1 < kN) { excl_out[base + 1] = run; run += c1; }
    if (base + 2 < kN) { excl_out[base + 2] = run; run += c2; }
    if (base + 3 < kN) { excl_out[base + 3] = run; run += c3; }
}

__global__ void scan2_k(const int* __restrict__ blk_sum, int* __restrict__ blk_off) {
    __shared__ int sd[256];
    int t = threadIdx.x;
    int v = (t < kNB) ? blk_sum[t] : 0;
    sd[t] = v;
    __syncthreads();
#pragma unroll
    for (int off = 1; off < 256; off <<= 1) {
        int u = (t >= off) ? sd[t - off] : 0;
        __syncthreads();
        sd[t] += u;
        __syncthreads();
    }
    if (t < kNB) blk_off[t] = sd[t] - v;
}

__global__ void scan3_k(int* __restrict__ rp, int* __restrict__ rf,
                        const int* __restrict__ blk_off) {
    int b = blockIdx.x, t = threadIdx.x;
    int base = b * kChunk + t * 4;
    int o = blk_off[b];
#pragma unroll
    for (int k = 0; k < 4; ++k) {
        int i = base + k;
        if (i < kN) { int v = rp[i] + o; rp[i] = v; rf[i] = v; }
    }
    if (b == 0 && t == 0) rp[kN] = kNnz;
}

__global__ void scatter_k(const int* __restrict__ rows, const int* __restrict__ cols,
                          const float* __restrict__ vals, int* __restrict__ rf,
                          int2* __restrict__ csr) {
    int e = blockIdx.x * blockDim.x + threadIdx.x;
    if (e >= kNnz) return;
    int r = rows[e];
    int pos = atomicAdd(&rf[r], 1);
    csr[pos] = make_int2(cols[e], __float_as_int(vals[e]));
}

// ============ fused layer: pull-SpMM + cosine reweight + acc ============
// R6 restructure: one wave per row, but lanes are split as q = lane>>4 (edge
// slot, 4 edges concurrently) x sub = lane&15 (dim quad, float4 per lane).
// Each global_load_dwordx4 now covers 4 edges (1 KB/wave) -> 4x fewer VMEM
// instructions than the lane-per-dim scheme, and the x4-group inner body puts
// 16 edges (4 independent gathers) in flight per wave. Avg degree = 16, so a
// typical row completes its gather phase in ONE iteration with all loads
// concurrent. Cross-q partials fold with shfl_xor(16|32); dot/norm reduce
// over sub with shfl_xor(1|2|4|8); only the q==0 quarter-wave writes.
__global__ __launch_bounds__(256)
void layer_k(const int* __restrict__ rp, const int2* __restrict__ csr,
             const float* __restrict__ ego, const float* __restrict__ nrm,
             const float* __restrict__ xin, float* __restrict__ xout,
             float* __restrict__ acc) {
    int wid  = threadIdx.x >> 6;
    int lane = threadIdx.x & 63;
    int row  = blockIdx.x * 4 + wid;
    if (row >= kN) return;
    int q   = lane >> 4;        // edge slot within a group of 4
    int sub = lane & 15;        // dim quad: dims 4*sub .. 4*sub+3
    int p0 = rp[row];
    int p1 = rp[row + 1];

    float4 s = make_float4(0.f, 0.f, 0.f, 0.f);
    for (int base = p0; base < p1; base += 16) {
        int2  e[4];
        float w[4];
#pragma unroll
        for (int g = 0; g < 4; ++g) {
            int j  = base + g * 4 + q;
            bool v = j < p1;
            e[g] = csr[v ? j : p0];          // 16-lane broadcast load, 8 B
            w[g] = v ? __int_as_float(e[g].y) : 0.f;
        }
        float4 a[4];
#pragma unroll
        for (int g = 0; g < 4; ++g)
            a[g] = *(const float4*)(xin + (size_t)e[g].x * kEmb + sub * 4);
#pragma unroll
        for (int g = 0; g < 4; ++g) {
            s.x = fmaf(w[g], a[g].x, s.x);
            s.y = fmaf(w[g], a[g].y, s.y);
            s.z = fmaf(w[g], a[g].z, s.z);
            s.w = fmaf(w[g], a[g].w, s.w);
        }
    }
    // fold the 4 edge slots: lanes {l, l^16, l^32, l^48} hold partials of the
    // same dims -> after this, every lane has the final row vector slice.
#pragma unroll
    for (int o = 16; o <= 32; o <<= 1) {
        s.x += __shfl_xor(s.x, o, 64);
        s.y += __shfl_xor(s.y, o, 64);
        s.z += __shfl_xor(s.z, o, 64);
        s.w += __shfl_xor(s.w, o, 64);
    }
    size_t idx = (size_t)row * kEmb + sub * 4;
    const float4 ev = *(const float4*)(ego + idx);
    float d = s.x * ev.x + s.y * ev.y + s.z * ev.z + s.w * ev.w;
    float n = s.x * s.x + s.y * s.y + s.z * s.z + s.w * s.w;
    // reduce over sub (16 lanes within each q group; q groups are replicas)
#pragma unroll
    for (int o = 1; o <= 8; o <<= 1) {
        d += __shfl_xor(d, o, 64);
        n += __shfl_xor(n, o, 64);
    }
    float wgt = d / fmaxf(sqrtf(n) * nrm[row], kEps);
    if (q == 0) {   // one replica writes; guards acc+= from 4x duplication
        float4 xw = make_float4(wgt * s.x, wgt * s.y, wgt * s.z, wgt * s.w);
        *(float4*)(xout + idx) = xw;
        float4 av = *(const float4*)(acc + idx);
        av.x += xw.x; av.y += xw.y; av.z += xw.z; av.w += xw.w;
        *(float4*)(acc + idx) = av;
    }
}

// ================= fallback (atomic) kernels =================

__global__ void norm_init_full_k(const float* __restrict__ ego, float* __restrict__ nrm,
                                 float* __restrict__ x, float* __restrict__ acc) {
    int wid  = threadIdx.x >> 6;
    int lane = threadIdx.x & 63;
    int row  = blockIdx.x * 4 + wid;
    if (row >= kN) return;
    size_t idx = (size_t)row * kEmb + lane;
    float e = ego[idx];
    x[idx]   = e;
    acc[idx] = e;
    float s = e * e;
#pragma unroll
    for (int o = 32; o >= 1; o >>= 1) s += __shfl_xor(s, o, 64);
    if (lane == 0) nrm[row] = sqrtf(s);
}

__global__ void spmm_k(const int* __restrict__ rows, const int* __restrict__ cols,
                       const float* __restrict__ vals, const float* __restrict__ x,
                       float* __restrict__ y) {
    long long t = (long long)blockIdx.x * blockDim.x + threadIdx.x;
    int e = (int)(t >> 6);
    if (e >= kNnz) return;
    int lane = threadIdx.x & 63;
    atomicAdd(y + (size_t)rows[e] * kEmb + lane, vals[e] * x[(size_t)cols[e] * kEmb + lane]);
}

__global__ void weight_k(const float* __restrict__ ego, const float* __restrict__ nrm,
                         const float* __restrict__ y, float* __restrict__ x,
                         float* __restrict__ acc) {
    int wid  = threadIdx.x >> 6;
    int lane = threadIdx.x & 63;
    int row  = blockIdx.x * 4 + wid;
    if (row >= kN) return;
    size_t idx = (size_t)row * kEmb + lane;
    float yv = y[idx];
    float ev = ego[idx];
    float d = yv * ev;
    float n = yv * yv;
#pragma unroll
    for (int o = 32; o >= 1; o >>= 1) {
        d += __shfl_xor(d, o, 64);
        n += __shfl_xor(n, o, 64);
    }
    float w  = d / fmaxf(sqrtf(n) * nrm[row], kEps);
    float xw = w * yv;
    x[idx] = xw;
    acc[idx] += xw;
}

// ================= launch =================

extern "C" void kernel_launch(void* const* d_in, const int* in_sizes, int n_in,
                              void* d_out, int out_size, void* d_ws, size_t ws_size,
                              hipStream_t stream) {
    const float* user_fea = (const float*)d_in[0];
    const float* item_fea = (const float*)d_in[1];
    const float* prompt   = (const float*)d_in[2];
    const float* mlp_w    = (const float*)d_in[3];
    const float* mlp_b    = (const float*)d_in[4];
    const int*   adj_rows = (const int*)d_in[5];
    const int*   adj_cols = (const int*)d_in[6];
    const float* adj_vals = (const float*)d_in[7];
    float* acc = (float*)d_out;   // running layer sum accumulates in-place in d_out

    const size_t NE = (size_t)kN * kEmb;  // 9.6M
    float* ws = (float*)d_ws;

    // ---- CSR-path workspace layout (4-byte units) ----
    size_t off = 0;
    float* f_ego = ws + off; off += NE;
    float* f_xa  = ws + off; off += NE;
    float* f_xb  = ws + off; off += NE;
    float* f_nrm = ws + off; off += kN;
    float* f_ps  = ws + off; off += 64;
    int* row_cnt  = (int*)(ws + off); off += kN;
    int* row_ptr  = (int*)(ws + off); off += kN + 1;
    int* row_fill = (int*)(ws + off); off += kN;
    int* blk_sum  = (int*)(ws + off); off += kNB;
    int* blk_off  = (int*)(ws + off); off += kNB;
    off = (off + 1) & ~(size_t)1;                   // 8B-align csr
    int2* csr = (int2*)(ws + off); off += (size_t)kNnz * 2;
    const bool use_csr = ws_size >= off * 4;

    // ---- common init ----
    prompt_sum_k<<<1, 64, 0, stream>>>(prompt, f_ps);
    user_ego_k<<<(kNUser * kEmb + 255) / 256, 256, 0, stream>>>(user_fea, f_ps, f_ego);
    item_ego_k<<<(kNItem + kRowsBlk - 1) / kRowsBlk, 256, 0, stream>>>(item_fea, mlp_w,
                                                                      mlp_b, f_ego);

    if (use_csr) {
        // ---- build CSR (amortized over 4 layers) ----
        hipMemsetAsync(row_cnt, 0, kN * sizeof(int), stream);
        hist_k<<<(kNnz + 255) / 256, 256, 0, stream>>>(adj_rows, row_cnt);
        scan1_k<<<kNB, 256, 0, stream>>>(row_cnt, row_ptr, blk_sum);
        scan2_k<<<1, 256, 0, stream>>>(blk_sum, blk_off);
        scan3_k<<<kNB, 256, 0, stream>>>(row_ptr, row_fill, blk_off);
        scatter_k<<<(kNnz + 255) / 256, 256, 0, stream>>>(adj_rows, adj_cols, adj_vals,
                                                          row_fill, csr);

        norm_init_csr_k<<<(kN + 3) / 4, 256, 0, stream>>>(f_ego, f_nrm, acc);

        // ---- 4 fused layers: ego -> xa -> xb -> xa -> xb ----
        const float* xin = f_ego;
        float* xout = f_xa;
        for (int l = 0; l < 4; ++l) {
            layer_k<<<(kN + 3) / 4, 256, 0, stream>>>(row_ptr, csr, f_ego, f_nrm,
                                                      xin, xout, acc);
            xin  = xout;
            xout = (xout == f_xa) ? f_xb : f_xa;
        }
    } else {
        // ---- fallback: atomic path ----
        float* f_x = f_xa;
        float* f_y = f_xb;
        norm_init_full_k<<<(kN + 3) / 4, 256, 0, stream>>>(f_ego, f_nrm, f_x, acc);
        for (int l = 0; l < 4; ++l) {
            hipMemsetAsync(f_y, 0, NE * sizeof(float), stream);
            spmm_k<<<(int)(((long long)kNnz * 64 + 255) / 256), 256, 0, stream>>>(
                adj_rows, adj_cols, adj_vals, f_x, f_y);
            weight_k<<<(kN + 3) / 4, 256, 0, stream>>>(f_ego, f_nrm, f_y, f_x, acc);
        }
    }
}

// Round 2
// 941.852 us; speedup vs baseline: 1.0636x; 1.0636x over previous
//
#include <hip/hip_runtime.h>

constexpr int kNUser = 100000;
constexpr int kNItem = 50000;
constexpr int kN     = 150000;
constexpr int kEmb   = 64;
constexpr int kFeat  = 384;
constexpr int kNnz   = 2400000;
constexpr float kEps = 1e-8f;

constexpr int kChunk = 1024;                       // elements per scan block
constexpr int kNB    = (kN + kChunk - 1) / kChunk; // 147 scan blocks

// binned-scatter params: 256 buckets of 586 rows; (rowrel<<18)|col packs into
// 28 bits (col < 2^18 = 262144, rowrel < 1024).
constexpr int kNBkt   = 256;
constexpr int kBR     = (kN + kNBkt - 1) / kNBkt;  // 586
constexpr int kChunkA = 4096;                      // edges per bucket_k WG
constexpr int kNWGA   = (kNnz + kChunkA - 1) / kChunkA;  // 586

// ================= shared init kernels =================

__global__ void prompt_sum_k(const float* __restrict__ p, float* __restrict__ out) {
    int d = threadIdx.x;  // 64 threads
    float s = 0.f;
#pragma unroll
    for (int i = 0; i < 8; ++i) s += p[i * kEmb + d];
    out[d] = s;
}

__global__ void user_ego_k(const float* __restrict__ uf, const float* __restrict__ ps,
                           float* __restrict__ ego) {
    int i = blockIdx.x * blockDim.x + threadIdx.x;
    if (i >= kNUser * kEmb) return;
    ego[i] = uf[i] + ps[i & 63];
}

// ---- item MLP: block = 64 rows; A staged through LDS (coalesced), compute
// reads A as wave-uniform ds_read_b128 broadcasts.
constexpr int kRW      = 16;   // rows per wave
constexpr int kRowsBlk = 64;   // rows per block (4 waves)
constexpr int kKc      = 32;   // K-chunk

__global__ __launch_bounds__(256, 2)
void item_ego_k(const float* __restrict__ itf, const float* __restrict__ w,
                const float* __restrict__ b, float* __restrict__ ego) {
    __shared__ float lds_a[kRowsBlk * kKc];  // 8 KB
    int t      = threadIdx.x;
    int wid    = t >> 6;
    int lane   = t & 63;
    int blk_r0 = blockIdx.x * kRowsBlk;

    float acc[kRW];
#pragma unroll
    for (int r = 0; r < kRW; ++r) acc[r] = 0.f;

    int srow = t >> 3;             // 0..31
    int scol = (t & 7) * 4;        // 0,4,..,28

    for (int kc = 0; kc < kFeat; kc += kKc) {
        __syncthreads();  // previous-chunk LDS reads done
        // ---- stage A tile: 64 rows x 32 k = 2048 floats, 2 float4/thread ----
        {
            const float4 z = make_float4(0.f, 0.f, 0.f, 0.f);
            int gr0 = blk_r0 + srow;
            int gr1 = gr0 + 32;
            float4 v0 = (gr0 < kNItem)
                ? *(const float4*)(itf + (size_t)gr0 * kFeat + kc + scol) : z;
            float4 v1 = (gr1 < kNItem)
                ? *(const float4*)(itf + (size_t)gr1 * kFeat + kc + scol) : z;
            *(float4*)(lds_a + srow * kKc + scol)        = v0;
            *(float4*)(lds_a + (srow + 32) * kKc + scol) = v1;
        }
        // ---- W chunk into registers (coalesced, independent of LDS) ----
        float wreg[kKc];
#pragma unroll
        for (int k = 0; k < kKc; ++k) wreg[k] = w[(kc + k) * kEmb + lane];
        __syncthreads();  // staging visible
        // ---- compute: wave-uniform LDS broadcasts ----
#pragma unroll
        for (int r = 0; r < kRW; ++r) {
            const float4* av = (const float4*)(lds_a + (wid * kRW + r) * kKc);
#pragma unroll
            for (int q = 0; q < 8; ++q) {
                float4 a = av[q];
                acc[r] = fmaf(a.x, wreg[q * 4 + 0], acc[r]);
                acc[r] = fmaf(a.y, wreg[q * 4 + 1], acc[r]);
                acc[r] = fmaf(a.z, wreg[q * 4 + 2], acc[r]);
                acc[r] = fmaf(a.w, wreg[q * 4 + 3], acc[r]);
            }
        }
    }
    float bv = b[lane];
#pragma unroll
    for (int r = 0; r < kRW; ++r) {
        int row = blk_r0 + wid * kRW + r;
        if (row < kNItem)
            ego[(size_t)(kNUser + row) * kEmb + lane] = tanhf(acc[r] + bv);
    }
}

// nrm + acc init (CSR path: layer 0 reads ego directly, no x copy needed)
__global__ void norm_init_csr_k(const float* __restrict__ ego, float* __restrict__ nrm,
                                float* __restrict__ acc) {
    int wid  = threadIdx.x >> 6;
    int lane = threadIdx.x & 63;
    int row  = blockIdx.x * 4 + wid;
    if (row >= kN) return;
    size_t idx = (size_t)row * kEmb + lane;
    float e = ego[idx];
    acc[idx] = e;
    float s = e * e;
#pragma unroll
    for (int o = 32; o >= 1; o >>= 1) s += __shfl_xor(s, o, 64);
    if (lane == 0) nrm[row] = sqrtf(s);
}

// ================= CSR build =================

__global__ void hist_k(const int* __restrict__ rows, int* __restrict__ cnt) {
    int e = blockIdx.x * blockDim.x + threadIdx.x;
    if (e < kNnz) atomicAdd(&cnt[rows[e]], 1);
}

__global__ void scan1_k(const int* __restrict__ cnt, int* __restrict__ excl_out,
                        int* __restrict__ blk_sum) {
    __shared__ int sd[256];
    int b = blockIdx.x, t = threadIdx.x;
    int base = b * kChunk + t * 4;
    int c0 = (base + 0 < kN) ? cnt[base + 0] : 0;
    int c1 = (base + 1 < kN) ? cnt[base + 1] : 0;
    int c2 = (base + 2 < kN) ? cnt[base + 2] : 0;
    int c3 = (base + 3 < kN) ? cnt[base + 3] : 0;
    int tsum = c0 + c1 + c2 + c3;
    sd[t] = tsum;
    __syncthreads();
#pragma unroll
    for (int off = 1; off < 256; off <<= 1) {
        int v = (t >= off) ? sd[t - off] : 0;
        __syncthreads();
        sd[t] += v;
        __syncthreads();
    }
    int excl = sd[t] - tsum;
    if (t == 255) blk_sum[b] = sd[255];
    int run = excl;
    if (base + 0 < kN) { excl_out[base + 0] = run; run += c0; }
    if (base + 1 < kN) { excl_out[base + 1] = run; run += c1; }
    if (base + 2 < kN) { excl_out[base + 2] = run; run += c2; }
    if (base + 3 < kN) { excl_out[base + 3] = run; run += c3; }
}

__global__ void scan2_k(const int* __restrict__ blk_sum, int* __restrict__ blk_off) {
    __shared__ int sd[256];
    int t = threadIdx.x;
    int v = (t < kNB) ? blk_sum[t] : 0;
    sd[t] = v;
    __syncthreads();
#pragma unroll
    for (int off = 1; off < 256; off <<= 1) {
        int u = (t >= off) ? sd[t - off] : 0;
        __syncthreads();
        sd[t] += u;
        __syncthreads();
    }
    if (t < kNB) blk_off[t] = sd[t] - v;
}

__global__ void scan3_k(int* __restrict__ rp, int* __restrict__ rf,
                        const int* __restrict__ blk_off) {
    int b = blockIdx.x, t = threadIdx.x;
    int base = b * kChunk + t * 4;
    int o = blk_off[b];
#pragma unroll
    for (int k = 0; k < 4; ++k) {
        int i = base + k;
        if (i < kN) { int v = rp[i] + o; rp[i] = v; rf[i] = v; }
    }
    if (b == 0 && t == 0) rp[kN] = kNnz;
}

// bucket bases: bbase[b] = row_ptr[min(b*kBR, kN)]; bbase[kNBkt] = kNnz
__global__ void bbase_k(const int* __restrict__ rp, int* __restrict__ bbase) {
    int b = blockIdx.x * blockDim.x + threadIdx.x;
    if (b <= kNBkt) {
        int r = b * kBR;
        bbase[b] = rp[r < kN ? r : kN];
    }
}

// phase A: partition edges into 256 row-range buckets. LDS histogram + one
// global atomicAdd per (WG,bucket) reserves a contiguous run (~16 edges =
// 128 B) -> near-full 64B-line writes instead of random 8B scatter.
// entry packs (rowrel<<18)|col in .x, val bits in .y.
__global__ __launch_bounds__(256)
void bucket_k(const int* __restrict__ rows, const int* __restrict__ cols,
              const float* __restrict__ vals, const int* __restrict__ bbase,
              int* __restrict__ bfill, int2* __restrict__ tmp) {
    __shared__ int cnt[kNBkt];
    __shared__ int wgbase[kNBkt];
    int t  = threadIdx.x;
    int e0 = blockIdx.x * kChunkA;
    for (int i = t; i < kNBkt; i += 256) cnt[i] = 0;
    __syncthreads();
    int myb[kChunkA / 256];
    int myoff[kChunkA / 256];
#pragma unroll
    for (int k = 0; k < kChunkA / 256; ++k) {
        int e = e0 + k * 256 + t;                 // coalesced
        if (e < kNnz) {
            int b = rows[e] / kBR;                // const-divisor magic mul
            myb[k]   = b;
            myoff[k] = atomicAdd(&cnt[b], 1);     // LDS atomic
        } else {
            myb[k] = -1;
        }
    }
    __syncthreads();
    for (int i = t; i < kNBkt; i += 256)
        wgbase[i] = cnt[i] ? atomicAdd(&bfill[i], cnt[i]) : 0;
    __syncthreads();
#pragma unroll
    for (int k = 0; k < kChunkA / 256; ++k) {
        int b = myb[k];
        if (b < 0) continue;
        int e = e0 + k * 256 + t;
        int pos = bbase[b] + wgbase[b] + myoff[k];
        int rowrel = rows[e] - b * kBR;           // re-read, L2-hot
        tmp[pos] = make_int2((rowrel << 18) | cols[e], __float_as_int(vals[e]));
    }
}

// phase B: one WG per bucket; sequential reads, final placement via rf atomic.
// rf window (586 ints) and csr window (~75 KB) stay L2-resident -> lines fill
// before eviction, killing the 7.6x write amplification of the flat scatter.
__global__ __launch_bounds__(256)
void debucket_k(const int2* __restrict__ tmp, const int* __restrict__ bbase,
                int* __restrict__ rf, int2* __restrict__ csr) {
    int b  = blockIdx.x;
    int t  = threadIdx.x;
    int j0 = bbase[b];
    int j1 = bbase[b + 1];
    int rbase = b * kBR;
    for (int jb = j0; jb < j1; jb += 1024) {
        int2 e[4];
        int  pos[4];
        bool v[4];
#pragma unroll
        for (int q = 0; q < 4; ++q) {
            int j = jb + q * 256 + t;
            v[q] = j < j1;
            if (v[q]) e[q] = tmp[j];
        }
#pragma unroll
        for (int q = 0; q < 4; ++q)
            if (v[q]) {
                int row = rbase + (int)((unsigned)e[q].x >> 18);
                pos[q] = atomicAdd(&rf[row], 1);
            }
#pragma unroll
        for (int q = 0; q < 4; ++q)
            if (v[q]) csr[pos[q]] = make_int2(e[q].x & 0x3FFFF, e[q].y);
    }
}

// ============ fused layer: pull-SpMM + cosine reweight + acc ============
// one wave per row; q = lane>>4 (edge slot, 4 edges concurrently) x
// sub = lane&15 (dim quad, float4 per lane). Each global_load_dwordx4 covers
// 4 edges; 16 edges (4 independent gathers) in flight per wave.
__global__ __launch_bounds__(256)
void layer_k(const int* __restrict__ rp, const int2* __restrict__ csr,
             const float* __restrict__ ego, const float* __restrict__ nrm,
             const float* __restrict__ xin, float* __restrict__ xout,
             float* __restrict__ acc) {
    int wid  = threadIdx.x >> 6;
    int lane = threadIdx.x & 63;
    int row  = blockIdx.x * 4 + wid;
    if (row >= kN) return;
    int q   = lane >> 4;        // edge slot within a group of 4
    int sub = lane & 15;        // dim quad: dims 4*sub .. 4*sub+3
    int p0 = rp[row];
    int p1 = rp[row + 1];

    float4 s = make_float4(0.f, 0.f, 0.f, 0.f);
    for (int base = p0; base < p1; base += 16) {
        int2  e[4];
        float w[4];
#pragma unroll
        for (int g = 0; g < 4; ++g) {
            int j  = base + g * 4 + q;
            bool v = j < p1;
            e[g] = csr[v ? j : p0];          // 16-lane broadcast load, 8 B
            w[g] = v ? __int_as_float(e[g].y) : 0.f;
        }
        float4 a[4];
#pragma unroll
        for (int g = 0; g < 4; ++g)
            a[g] = *(const float4*)(xin + (size_t)e[g].x * kEmb + sub * 4);
#pragma unroll
        for (int g = 0; g < 4; ++g) {
            s.x = fmaf(w[g], a[g].x, s.x);
            s.y = fmaf(w[g], a[g].y, s.y);
            s.z = fmaf(w[g], a[g].z, s.z);
            s.w = fmaf(w[g], a[g].w, s.w);
        }
    }
    // fold the 4 edge slots
#pragma unroll
    for (int o = 16; o <= 32; o <<= 1) {
        s.x += __shfl_xor(s.x, o, 64);
        s.y += __shfl_xor(s.y, o, 64);
        s.z += __shfl_xor(s.z, o, 64);
        s.w += __shfl_xor(s.w, o, 64);
    }
    size_t idx = (size_t)row * kEmb + sub * 4;
    const float4 ev = *(const float4*)(ego + idx);
    float d = s.x * ev.x + s.y * ev.y + s.z * ev.z + s.w * ev.w;
    float n = s.x * s.x + s.y * s.y + s.z * s.z + s.w * s.w;
#pragma unroll
    for (int o = 1; o <= 8; o <<= 1) {
        d += __shfl_xor(d, o, 64);
        n += __shfl_xor(n, o, 64);
    }
    float wgt = d / fmaxf(sqrtf(n) * nrm[row], kEps);
    if (q == 0) {   // one replica writes; guards acc+= from 4x duplication
        float4 xw = make_float4(wgt * s.x, wgt * s.y, wgt * s.z, wgt * s.w);
        *(float4*)(xout + idx) = xw;
        float4 av = *(const float4*)(acc + idx);
        av.x += xw.x; av.y += xw.y; av.z += xw.z; av.w += xw.w;
        *(float4*)(acc + idx) = av;
    }
}

// ================= fallback (atomic) kernels =================

__global__ void norm_init_full_k(const float* __restrict__ ego, float* __restrict__ nrm,
                                 float* __restrict__ x, float* __restrict__ acc) {
    int wid  = threadIdx.x >> 6;
    int lane = threadIdx.x & 63;
    int row  = blockIdx.x * 4 + wid;
    if (row >= kN) return;
    size_t idx = (size_t)row * kEmb + lane;
    float e = ego[idx];
    x[idx]   = e;
    acc[idx] = e;
    float s = e * e;
#pragma unroll
    for (int o = 32; o >= 1; o >>= 1) s += __shfl_xor(s, o, 64);
    if (lane == 0) nrm[row] = sqrtf(s);
}

__global__ void spmm_k(const int* __restrict__ rows, const int* __restrict__ cols,
                       const float* __restrict__ vals, const float* __restrict__ x,
                       float* __restrict__ y) {
    long long t = (long long)blockIdx.x * blockDim.x + threadIdx.x;
    int e = (int)(t >> 6);
    if (e >= kNnz) return;
    int lane = threadIdx.x & 63;
    atomicAdd(y + (size_t)rows[e] * kEmb + lane, vals[e] * x[(size_t)cols[e] * kEmb + lane]);
}

__global__ void weight_k(const float* __restrict__ ego, const float* __restrict__ nrm,
                         const float* __restrict__ y, float* __restrict__ x,
                         float* __restrict__ acc) {
    int wid  = threadIdx.x >> 6;
    int lane = threadIdx.x & 63;
    int row  = blockIdx.x * 4 + wid;
    if (row >= kN) return;
    size_t idx = (size_t)row * kEmb + lane;
    float yv = y[idx];
    float ev = ego[idx];
    float d = yv * ev;
    float n = yv * yv;
#pragma unroll
    for (int o = 32; o >= 1; o >>= 1) {
        d += __shfl_xor(d, o, 64);
        n += __shfl_xor(n, o, 64);
    }
    float w  = d / fmaxf(sqrtf(n) * nrm[row], kEps);
    float xw = w * yv;
    x[idx] = xw;
    acc[idx] += xw;
}

// ================= launch =================

extern "C" void kernel_launch(void* const* d_in, const int* in_sizes, int n_in,
                              void* d_out, int out_size, void* d_ws, size_t ws_size,
                              hipStream_t stream) {
    const float* user_fea = (const float*)d_in[0];
    const float* item_fea = (const float*)d_in[1];
    const float* prompt   = (const float*)d_in[2];
    const float* mlp_w    = (const float*)d_in[3];
    const float* mlp_b    = (const float*)d_in[4];
    const int*   adj_rows = (const int*)d_in[5];
    const int*   adj_cols = (const int*)d_in[6];
    const float* adj_vals = (const float*)d_in[7];
    float* acc = (float*)d_out;   // running layer sum accumulates in-place in d_out

    const size_t NE = (size_t)kN * kEmb;  // 9.6M
    float* ws = (float*)d_ws;

    // ---- CSR-path workspace layout (4-byte units) ----
    size_t off = 0;
    float* f_ego = ws + off; off += NE;
    float* f_xa  = ws + off; off += NE;   // doubles as bucket tmp (4.8M ints < 9.6M)
    float* f_xb  = ws + off; off += NE;
    float* f_nrm = ws + off; off += kN;
    float* f_ps  = ws + off; off += 64;
    int* row_cnt  = (int*)(ws + off); off += kN;
    int* row_ptr  = (int*)(ws + off); off += kN + 1;
    int* row_fill = (int*)(ws + off); off += kN;
    int* blk_sum  = (int*)(ws + off); off += kNB;
    int* blk_off  = (int*)(ws + off); off += kNB;
    int* bbase    = (int*)(ws + off); off += kNBkt + 1;
    int* bfill    = (int*)(ws + off); off += kNBkt;
    off = (off + 1) & ~(size_t)1;                   // 8B-align csr
    int2* csr = (int2*)(ws + off); off += (size_t)kNnz * 2;
    const bool use_csr = ws_size >= off * 4;

    // ---- common init ----
    prompt_sum_k<<<1, 64, 0, stream>>>(prompt, f_ps);
    user_ego_k<<<(kNUser * kEmb + 255) / 256, 256, 0, stream>>>(user_fea, f_ps, f_ego);
    item_ego_k<<<(kNItem + kRowsBlk - 1) / kRowsBlk, 256, 0, stream>>>(item_fea, mlp_w,
                                                                      mlp_b, f_ego);

    if (use_csr) {
        int2* tmp = (int2*)f_xa;   // bucket staging, free until layer 0 output
        // ---- build CSR via 2-phase binned counting sort ----
        hipMemsetAsync(row_cnt, 0, kN * sizeof(int), stream);
        hipMemsetAsync(bfill, 0, kNBkt * sizeof(int), stream);
        hist_k<<<(kNnz + 255) / 256, 256, 0, stream>>>(adj_rows, row_cnt);
        scan1_k<<<kNB, 256, 0, stream>>>(row_cnt, row_ptr, blk_sum);
        scan2_k<<<1, 256, 0, stream>>>(blk_sum, blk_off);
        scan3_k<<<kNB, 256, 0, stream>>>(row_ptr, row_fill, blk_off);
        bbase_k<<<2, 256, 0, stream>>>(row_ptr, bbase);
        bucket_k<<<kNWGA, 256, 0, stream>>>(adj_rows, adj_cols, adj_vals,
                                            bbase, bfill, tmp);
        debucket_k<<<kNBkt, 256, 0, stream>>>(tmp, bbase, row_fill, csr);

        norm_init_csr_k<<<(kN + 3) / 4, 256, 0, stream>>>(f_ego, f_nrm, acc);

        // ---- 4 fused layers: ego -> xa -> xb -> xa -> xb ----
        const float* xin = f_ego;
        float* xout = f_xa;
        for (int l = 0; l < 4; ++l) {
            layer_k<<<(kN + 3) / 4, 256, 0, stream>>>(row_ptr, csr, f_ego, f_nrm,
                                                      xin, xout, acc);
            xin  = xout;
            xout = (xout == f_xa) ? f_xb : f_xa;
        }
    } else {
        // ---- fallback: atomic path ----
        float* f_x = f_xa;
        float* f_y = f_xb;
        norm_init_full_k<<<(kN + 3) / 4, 256, 0, stream>>>(f_ego, f_nrm, f_x, acc);
        for (int l = 0; l < 4; ++l) {
            hipMemsetAsync(f_y, 0, NE * sizeof(float), stream);
            spmm_k<<<(int)(((long long)kNnz * 64 + 255) / 256), 256, 0, stream>>>(
                adj_rows, adj_cols, adj_vals, f_x, f_y);
            weight_k<<<(kN + 3) / 4, 256, 0, stream>>>(f_ego, f_nrm, f_y, f_x, acc);
        }
    }
}

// Round 3
// 869.929 us; speedup vs baseline: 1.1515x; 1.0827x over previous
//
#include <hip/hip_runtime.h>

constexpr int kNUser = 100000;
constexpr int kNItem = 50000;
constexpr int kN     = 150000;
constexpr int kEmb   = 64;
constexpr int kFeat  = 384;
constexpr int kNnz   = 2400000;
constexpr float kEps = 1e-8f;

constexpr int kChunk = 1024;                       // elements per scan block
constexpr int kNB    = (kN + kChunk - 1) / kChunk; // 147 scan blocks

// binned-scatter params: 256 buckets of 586 rows; (rowrel<<18)|col packs into
// 28 bits (col < 2^18 = 262144, rowrel < 1024).
constexpr int kNBkt   = 256;
constexpr int kBR     = (kN + kNBkt - 1) / kNBkt;  // 586
constexpr int kChunkA = 4096;                      // edges per bucket_k WG
constexpr int kNWGA   = (kNnz + kChunkA - 1) / kChunkA;  // 586

// item-MLP MFMA geometry: 12 k-steps (K=384/32), 4 n-tiles (N=64/16)
constexpr int kKS     = kFeat / 32;   // 12
constexpr int kNT     = kEmb / 16;    // 4
constexpr int kWElems = kKS * kNT * 64 * 8;  // 24576 pre-split W frag elems

typedef __attribute__((ext_vector_type(8))) short short8v;   // 8 bf16 (4 VGPR)
typedef __attribute__((ext_vector_type(4))) float floatx4;

__device__ inline unsigned short f2bf(float f) {   // fp32 -> bf16 bits, RNE
    unsigned u = __float_as_uint(f);
    return (unsigned short)((u + 0x7FFFu + ((u >> 16) & 1u)) >> 16);
}
__device__ inline float bf2f(unsigned short h) {
    return __uint_as_float((unsigned)h << 16);
}

// ================= shared init kernels =================

__global__ void prompt_sum_k(const float* __restrict__ p, float* __restrict__ out) {
    int d = threadIdx.x;  // 64 threads
    float s = 0.f;
#pragma unroll
    for (int i = 0; i < 8; ++i) s += p[i * kEmb + d];
    out[d] = s;
}

__global__ void user_ego_k(const float* __restrict__ uf, const float* __restrict__ ps,
                           float* __restrict__ ego) {
    int i = blockIdx.x * blockDim.x + threadIdx.x;
    if (i >= kNUser * kEmb) return;
    ego[i] = uf[i] + ps[i & 63];
}

// ---- W pre-split: fragment-ordered bf16 hi/lo. Layout:
// idx = ((ks*kNT + nt)*64 + lane)*8 + j  ->  w[k = ks*32 + (lane>>4)*8 + j]
//                                            [n = nt*16 + (lane&15)]
__global__ void wsplit_k(const float* __restrict__ w, unsigned short* __restrict__ whi,
                         unsigned short* __restrict__ wlo) {
    int t = blockIdx.x * 256 + threadIdx.x;
    if (t >= kWElems) return;
    int j    = t & 7;
    int lane = (t >> 3) & 63;
    int nt   = (t >> 9) & 3;
    int ks   = t >> 11;
    int k = ks * 32 + (lane >> 4) * 8 + j;
    int n = nt * 16 + (lane & 15);
    float v = w[k * kEmb + n];
    unsigned short h = f2bf(v);
    whi[t] = h;
    wlo[t] = f2bf(v - bf2f(h));
}

// ---- item MLP via bf16x2-split MFMA (fp32-equivalent: drops only the
// a_lo*w_lo term, ~2^-18 relative). R7: the fp32-VALU version was
// latency-bound at 151us (VALUBusy 28%, occ 20%); MFMA floor ~3us + memory
// floor ~15us. Wave = 16 rows x 64 cols = 4x mfma_f32_16x16x32_bf16 tiles;
// separate hi/lo accumulator chains (8 independent MFMA chains per wave).
__global__ __launch_bounds__(256)
void item_ego_mfma_k(const float* __restrict__ itf, const unsigned short* __restrict__ whi,
                     const unsigned short* __restrict__ wlo, const float* __restrict__ b,
                     float* __restrict__ ego) {
    int t    = threadIdx.x;
    int wid  = t >> 6;
    int lane = t & 63;
    int r0   = blockIdx.x * 64 + wid * 16;   // wave's first row
    int arow = r0 + (lane & 15);             // this lane's A row
    int kg   = lane >> 4;                    // k-group 0..3
    bool av  = arow < kNItem;                // uniform per wave (boundary % 16)
    const float* ap = itf + (size_t)(av ? arow : 0) * kFeat + kg * 8;

    const short8v* whv = (const short8v*)whi;
    const short8v* wlv = (const short8v*)wlo;

    floatx4 accH[kNT], accL[kNT];
#pragma unroll
    for (int nt = 0; nt < kNT; ++nt) {
        accH[nt] = (floatx4){0.f, 0.f, 0.f, 0.f};
        accL[nt] = (floatx4){0.f, 0.f, 0.f, 0.f};
    }

    for (int ks = 0; ks < kKS; ++ks) {
        const float4 z = make_float4(0.f, 0.f, 0.f, 0.f);
        float4 a0 = av ? *(const float4*)(ap + ks * 32)     : z;
        float4 a1 = av ? *(const float4*)(ap + ks * 32 + 4) : z;
        short8v ah, al;
#pragma unroll
        for (int j = 0; j < 8; ++j) {
            float f = (j < 4) ? ((const float*)&a0)[j] : ((const float*)&a1)[j - 4];
            unsigned short h = f2bf(f);
            ah[j] = (short)h;
            al[j] = (short)f2bf(f - bf2f(h));
        }
#pragma unroll
        for (int nt = 0; nt < kNT; ++nt) {
            short8v bh = whv[(ks * kNT + nt) * 64 + lane];
            short8v bl = wlv[(ks * kNT + nt) * 64 + lane];
            accH[nt] = __builtin_amdgcn_mfma_f32_16x16x32_bf16(ah, bh, accH[nt], 0, 0, 0);
            accL[nt] = __builtin_amdgcn_mfma_f32_16x16x32_bf16(ah, bl, accL[nt], 0, 0, 0);
            accL[nt] = __builtin_amdgcn_mfma_f32_16x16x32_bf16(al, bh, accL[nt], 0, 0, 0);
        }
    }

    // C/D layout (verified m89/m91): col = lane&15, row = (lane>>4)*4 + reg
    int col0  = lane & 15;
    int rsub  = (lane >> 4) * 4;
#pragma unroll
    for (int nt = 0; nt < kNT; ++nt) {
        float bb = b[nt * 16 + col0];
#pragma unroll
        for (int r = 0; r < 4; ++r) {
            int row = r0 + rsub + r;
            if (row < kNItem)
                ego[(size_t)(kNUser + row) * kEmb + nt * 16 + col0] =
                    tanhf(accH[nt][r] + accL[nt][r] + bb);
        }
    }
}

// ---- fallback-path item MLP (fp32 VALU, LDS-staged) ----
constexpr int kRW      = 16;   // rows per wave
constexpr int kRowsBlk = 64;   // rows per block (4 waves)
constexpr int kKc      = 32;   // K-chunk

__global__ __launch_bounds__(256, 2)
void item_ego_k(const float* __restrict__ itf, const float* __restrict__ w,
                const float* __restrict__ b, float* __restrict__ ego) {
    __shared__ float lds_a[kRowsBlk * kKc];  // 8 KB
    int t      = threadIdx.x;
    int wid    = t >> 6;
    int lane   = t & 63;
    int blk_r0 = blockIdx.x * kRowsBlk;

    float acc[kRW];
#pragma unroll
    for (int r = 0; r < kRW; ++r) acc[r] = 0.f;

    int srow = t >> 3;             // 0..31
    int scol = (t & 7) * 4;        // 0,4,..,28

    for (int kc = 0; kc < kFeat; kc += kKc) {
        __syncthreads();
        {
            const float4 z = make_float4(0.f, 0.f, 0.f, 0.f);
            int gr0 = blk_r0 + srow;
            int gr1 = gr0 + 32;
            float4 v0 = (gr0 < kNItem)
                ? *(const float4*)(itf + (size_t)gr0 * kFeat + kc + scol) : z;
            float4 v1 = (gr1 < kNItem)
                ? *(const float4*)(itf + (size_t)gr1 * kFeat + kc + scol) : z;
            *(float4*)(lds_a + srow * kKc + scol)        = v0;
            *(float4*)(lds_a + (srow + 32) * kKc + scol) = v1;
        }
        float wreg[kKc];
#pragma unroll
        for (int k = 0; k < kKc; ++k) wreg[k] = w[(kc + k) * kEmb + lane];
        __syncthreads();
#pragma unroll
        for (int r = 0; r < kRW; ++r) {
            const float4* av = (const float4*)(lds_a + (wid * kRW + r) * kKc);
#pragma unroll
            for (int q = 0; q < 8; ++q) {
                float4 a = av[q];
                acc[r] = fmaf(a.x, wreg[q * 4 + 0], acc[r]);
                acc[r] = fmaf(a.y, wreg[q * 4 + 1], acc[r]);
                acc[r] = fmaf(a.z, wreg[q * 4 + 2], acc[r]);
                acc[r] = fmaf(a.w, wreg[q * 4 + 3], acc[r]);
            }
        }
    }
    float bv = b[lane];
#pragma unroll
    for (int r = 0; r < kRW; ++r) {
        int row = blk_r0 + wid * kRW + r;
        if (row < kNItem)
            ego[(size_t)(kNUser + row) * kEmb + lane] = tanhf(acc[r] + bv);
    }
}

// nrm + acc init (CSR path: layer 0 reads ego directly, no x copy needed)
__global__ void norm_init_csr_k(const float* __restrict__ ego, float* __restrict__ nrm,
                                float* __restrict__ acc) {
    int wid  = threadIdx.x >> 6;
    int lane = threadIdx.x & 63;
    int row  = blockIdx.x * 4 + wid;
    if (row >= kN) return;
    size_t idx = (size_t)row * kEmb + lane;
    float e = ego[idx];
    acc[idx] = e;
    float s = e * e;
#pragma unroll
    for (int o = 32; o >= 1; o >>= 1) s += __shfl_xor(s, o, 64);
    if (lane == 0) nrm[row] = sqrtf(s);
}

// ================= CSR build =================

__global__ void hist_k(const int* __restrict__ rows, int* __restrict__ cnt) {
    int e = blockIdx.x * blockDim.x + threadIdx.x;
    if (e < kNnz) atomicAdd(&cnt[rows[e]], 1);
}

__global__ void scan1_k(const int* __restrict__ cnt, int* __restrict__ excl_out,
                        int* __restrict__ blk_sum) {
    __shared__ int sd[256];
    int b = blockIdx.x, t = threadIdx.x;
    int base = b * kChunk + t * 4;
    int c0 = (base + 0 < kN) ? cnt[base + 0] : 0;
    int c1 = (base + 1 < kN) ? cnt[base + 1] : 0;
    int c2 = (base + 2 < kN) ? cnt[base + 2] : 0;
    int c3 = (base + 3 < kN) ? cnt[base + 3] : 0;
    int tsum = c0 + c1 + c2 + c3;
    sd[t] = tsum;
    __syncthreads();
#pragma unroll
    for (int off = 1; off < 256; off <<= 1) {
        int v = (t >= off) ? sd[t - off] : 0;
        __syncthreads();
        sd[t] += v;
        __syncthreads();
    }
    int excl = sd[t] - tsum;
    if (t == 255) blk_sum[b] = sd[255];
    int run = excl;
    if (base + 0 < kN) { excl_out[base + 0] = run; run += c0; }
    if (base + 1 < kN) { excl_out[base + 1] = run; run += c1; }
    if (base + 2 < kN) { excl_out[base + 2] = run; run += c2; }
    if (base + 3 < kN) { excl_out[base + 3] = run; run += c3; }
}

__global__ void scan2_k(const int* __restrict__ blk_sum, int* __restrict__ blk_off) {
    __shared__ int sd[256];
    int t = threadIdx.x;
    int v = (t < kNB) ? blk_sum[t] : 0;
    sd[t] = v;
    __syncthreads();
#pragma unroll
    for (int off = 1; off < 256; off <<= 1) {
        int u = (t >= off) ? sd[t - off] : 0;
        __syncthreads();
        sd[t] += u;
        __syncthreads();
    }
    if (t < kNB) blk_off[t] = sd[t] - v;
}

__global__ void scan3_k(int* __restrict__ rp, int* __restrict__ rf,
                        const int* __restrict__ blk_off) {
    int b = blockIdx.x, t = threadIdx.x;
    int base = b * kChunk + t * 4;
    int o = blk_off[b];
#pragma unroll
    for (int k = 0; k < 4; ++k) {
        int i = base + k;
        if (i < kN) { int v = rp[i] + o; rp[i] = v; rf[i] = v; }
    }
    if (b == 0 && t == 0) rp[kN] = kNnz;
}

// bucket bases: bbase[b] = row_ptr[min(b*kBR, kN)]; bbase[kNBkt] = kNnz
__global__ void bbase_k(const int* __restrict__ rp, int* __restrict__ bbase) {
    int b = blockIdx.x * blockDim.x + threadIdx.x;
    if (b <= kNBkt) {
        int r = b * kBR;
        bbase[b] = rp[r < kN ? r : kN];
    }
}

// phase A: partition edges into 256 row-range buckets (LDS histogram + one
// global atomicAdd per (WG,bucket) reserving a contiguous run).
__global__ __launch_bounds__(256)
void bucket_k(const int* __restrict__ rows, const int* __restrict__ cols,
              const float* __restrict__ vals, const int* __restrict__ bbase,
              int* __restrict__ bfill, int2* __restrict__ tmp) {
    __shared__ int cnt[kNBkt];
    __shared__ int wgbase[kNBkt];
    int t  = threadIdx.x;
    int e0 = blockIdx.x * kChunkA;
    for (int i = t; i < kNBkt; i += 256) cnt[i] = 0;
    __syncthreads();
    int myb[kChunkA / 256];
    int myoff[kChunkA / 256];
#pragma unroll
    for (int k = 0; k < kChunkA / 256; ++k) {
        int e = e0 + k * 256 + t;                 // coalesced
        if (e < kNnz) {
            int b = rows[e] / kBR;                // const-divisor magic mul
            myb[k]   = b;
            myoff[k] = atomicAdd(&cnt[b], 1);     // LDS atomic
        } else {
            myb[k] = -1;
        }
    }
    __syncthreads();
    for (int i = t; i < kNBkt; i += 256)
        wgbase[i] = cnt[i] ? atomicAdd(&bfill[i], cnt[i]) : 0;
    __syncthreads();
#pragma unroll
    for (int k = 0; k < kChunkA / 256; ++k) {
        int b = myb[k];
        if (b < 0) continue;
        int e = e0 + k * 256 + t;
        int pos = bbase[b] + wgbase[b] + myoff[k];
        int rowrel = rows[e] - b * kBR;           // re-read, L2-hot
        tmp[pos] = make_int2((rowrel << 18) | cols[e], __float_as_int(vals[e]));
    }
}

// phase B: one WG per bucket; sequential reads, final placement via rf atomic.
__global__ __launch_bounds__(256)
void debucket_k(const int2* __restrict__ tmp, const int* __restrict__ bbase,
                int* __restrict__ rf, int2* __restrict__ csr) {
    int b  = blockIdx.x;
    int t  = threadIdx.x;
    int j0 = bbase[b];
    int j1 = bbase[b + 1];
    int rbase = b * kBR;
    for (int jb = j0; jb < j1; jb += 1024) {
        int2 e[4];
        int  pos[4];
        bool v[4];
#pragma unroll
        for (int q = 0; q < 4; ++q) {
            int j = jb + q * 256 + t;
            v[q] = j < j1;
            if (v[q]) e[q] = tmp[j];
        }
#pragma unroll
        for (int q = 0; q < 4; ++q)
            if (v[q]) {
                int row = rbase + (int)((unsigned)e[q].x >> 18);
                pos[q] = atomicAdd(&rf[row], 1);
            }
#pragma unroll
        for (int q = 0; q < 4; ++q)
            if (v[q]) csr[pos[q]] = make_int2(e[q].x & 0x3FFFF, e[q].y);
    }
}

// ============ fused layer: pull-SpMM + cosine reweight + acc ============
__global__ __launch_bounds__(256)
void layer_k(const int* __restrict__ rp, const int2* __restrict__ csr,
             const float* __restrict__ ego, const float* __restrict__ nrm,
             const float* __restrict__ xin, float* __restrict__ xout,
             float* __restrict__ acc) {
    int wid  = threadIdx.x >> 6;
    int lane = threadIdx.x & 63;
    int row  = blockIdx.x * 4 + wid;
    if (row >= kN) return;
    int q   = lane >> 4;        // edge slot within a group of 4
    int sub = lane & 15;        // dim quad: dims 4*sub .. 4*sub+3
    int p0 = rp[row];
    int p1 = rp[row + 1];

    float4 s = make_float4(0.f, 0.f, 0.f, 0.f);
    for (int base = p0; base < p1; base += 16) {
        int2  e[4];
        float w[4];
#pragma unroll
        for (int g = 0; g < 4; ++g) {
            int j  = base + g * 4 + q;
            bool v = j < p1;
            e[g] = csr[v ? j : p0];          // 16-lane broadcast load, 8 B
            w[g] = v ? __int_as_float(e[g].y) : 0.f;
        }
        float4 a[4];
#pragma unroll
        for (int g = 0; g < 4; ++g)
            a[g] = *(const float4*)(xin + (size_t)e[g].x * kEmb + sub * 4);
#pragma unroll
        for (int g = 0; g < 4; ++g) {
            s.x = fmaf(w[g], a[g].x, s.x);
            s.y = fmaf(w[g], a[g].y, s.y);
            s.z = fmaf(w[g], a[g].z, s.z);
            s.w = fmaf(w[g], a[g].w, s.w);
        }
    }
#pragma unroll
    for (int o = 16; o <= 32; o <<= 1) {
        s.x += __shfl_xor(s.x, o, 64);
        s.y += __shfl_xor(s.y, o, 64);
        s.z += __shfl_xor(s.z, o, 64);
        s.w += __shfl_xor(s.w, o, 64);
    }
    size_t idx = (size_t)row * kEmb + sub * 4;
    const float4 ev = *(const float4*)(ego + idx);
    float d = s.x * ev.x + s.y * ev.y + s.z * ev.z + s.w * ev.w;
    float n = s.x * s.x + s.y * s.y + s.z * s.z + s.w * s.w;
#pragma unroll
    for (int o = 1; o <= 8; o <<= 1) {
        d += __shfl_xor(d, o, 64);
        n += __shfl_xor(n, o, 64);
    }
    float wgt = d / fmaxf(sqrtf(n) * nrm[row], kEps);
    if (q == 0) {   // one replica writes; guards acc+= from 4x duplication
        float4 xw = make_float4(wgt * s.x, wgt * s.y, wgt * s.z, wgt * s.w);
        *(float4*)(xout + idx) = xw;
        float4 av = *(const float4*)(acc + idx);
        av.x += xw.x; av.y += xw.y; av.z += xw.z; av.w += xw.w;
        *(float4*)(acc + idx) = av;
    }
}

// ================= fallback (atomic) kernels =================

__global__ void norm_init_full_k(const float* __restrict__ ego, float* __restrict__ nrm,
                                 float* __restrict__ x, float* __restrict__ acc) {
    int wid  = threadIdx.x >> 6;
    int lane = threadIdx.x & 63;
    int row  = blockIdx.x * 4 + wid;
    if (row >= kN) return;
    size_t idx = (size_t)row * kEmb + lane;
    float e = ego[idx];
    x[idx]   = e;
    acc[idx] = e;
    float s = e * e;
#pragma unroll
    for (int o = 32; o >= 1; o >>= 1) s += __shfl_xor(s, o, 64);
    if (lane == 0) nrm[row] = sqrtf(s);
}

__global__ void spmm_k(const int* __restrict__ rows, const int* __restrict__ cols,
                       const float* __restrict__ vals, const float* __restrict__ x,
                       float* __restrict__ y) {
    long long t = (long long)blockIdx.x * blockDim.x + threadIdx.x;
    int e = (int)(t >> 6);
    if (e >= kNnz) return;
    int lane = threadIdx.x & 63;
    atomicAdd(y + (size_t)rows[e] * kEmb + lane, vals[e] * x[(size_t)cols[e] * kEmb + lane]);
}

__global__ void weight_k(const float* __restrict__ ego, const float* __restrict__ nrm,
                         const float* __restrict__ y, float* __restrict__ x,
                         float* __restrict__ acc) {
    int wid  = threadIdx.x >> 6;
    int lane = threadIdx.x & 63;
    int row  = blockIdx.x * 4 + wid;
    if (row >= kN) return;
    size_t idx = (size_t)row * kEmb + lane;
    float yv = y[idx];
    float ev = ego[idx];
    float d = yv * ev;
    float n = yv * yv;
#pragma unroll
    for (int o = 32; o >= 1; o >>= 1) {
        d += __shfl_xor(d, o, 64);
        n += __shfl_xor(n, o, 64);
    }
    float w  = d / fmaxf(sqrtf(n) * nrm[row], kEps);
    float xw = w * yv;
    x[idx] = xw;
    acc[idx] += xw;
}

// ================= launch =================

extern "C" void kernel_launch(void* const* d_in, const int* in_sizes, int n_in,
                              void* d_out, int out_size, void* d_ws, size_t ws_size,
                              hipStream_t stream) {
    const float* user_fea = (const float*)d_in[0];
    const float* item_fea = (const float*)d_in[1];
    const float* prompt   = (const float*)d_in[2];
    const float* mlp_w    = (const float*)d_in[3];
    const float* mlp_b    = (const float*)d_in[4];
    const int*   adj_rows = (const int*)d_in[5];
    const int*   adj_cols = (const int*)d_in[6];
    const float* adj_vals = (const float*)d_in[7];
    float* acc = (float*)d_out;   // running layer sum accumulates in-place in d_out

    const size_t NE = (size_t)kN * kEmb;  // 9.6M
    float* ws = (float*)d_ws;

    // ---- CSR-path workspace layout (4-byte units) ----
    size_t off = 0;
    float* f_ego = ws + off; off += NE;
    float* f_xa  = ws + off; off += NE;   // doubles as bucket tmp (4.8M ints < 9.6M)
    float* f_xb  = ws + off; off += NE;
    float* f_nrm = ws + off; off += kN;
    float* f_ps  = ws + off; off += 64;
    int* row_cnt  = (int*)(ws + off); off += kN;
    int* row_ptr  = (int*)(ws + off); off += kN + 1;
    int* row_fill = (int*)(ws + off); off += kN;
    int* blk_sum  = (int*)(ws + off); off += kNB;
    int* blk_off  = (int*)(ws + off); off += kNB;
    int* bbase    = (int*)(ws + off); off += kNBkt + 1;
    int* bfill    = (int*)(ws + off); off += kNBkt;
    off = (off + 3) & ~(size_t)3;                   // 16B-align W frags
    unsigned short* whi = (unsigned short*)(ws + off); off += kWElems / 2;
    unsigned short* wlo = (unsigned short*)(ws + off); off += kWElems / 2;
    off = (off + 1) & ~(size_t)1;                   // 8B-align csr
    int2* csr = (int2*)(ws + off); off += (size_t)kNnz * 2;
    const bool use_csr = ws_size >= off * 4;

    // ---- common init ----
    prompt_sum_k<<<1, 64, 0, stream>>>(prompt, f_ps);
    user_ego_k<<<(kNUser * kEmb + 255) / 256, 256, 0, stream>>>(user_fea, f_ps, f_ego);

    if (use_csr) {
        // item MLP via bf16x2-split MFMA
        wsplit_k<<<(kWElems + 255) / 256, 256, 0, stream>>>(mlp_w, whi, wlo);
        item_ego_mfma_k<<<(kNItem + 63) / 64, 256, 0, stream>>>(item_fea, whi, wlo,
                                                                mlp_b, f_ego);

        int2* tmp = (int2*)f_xa;   // bucket staging, free until layer 0 output
        // ---- build CSR via 2-phase binned counting sort ----
        hipMemsetAsync(row_cnt, 0, kN * sizeof(int), stream);
        hipMemsetAsync(bfill, 0, kNBkt * sizeof(int), stream);
        hist_k<<<(kNnz + 255) / 256, 256, 0, stream>>>(adj_rows, row_cnt);
        scan1_k<<<kNB, 256, 0, stream>>>(row_cnt, row_ptr, blk_sum);
        scan2_k<<<1, 256, 0, stream>>>(blk_sum, blk_off);
        scan3_k<<<kNB, 256, 0, stream>>>(row_ptr, row_fill, blk_off);
        bbase_k<<<2, 256, 0, stream>>>(row_ptr, bbase);
        bucket_k<<<kNWGA, 256, 0, stream>>>(adj_rows, adj_cols, adj_vals,
                                            bbase, bfill, tmp);
        debucket_k<<<kNBkt, 256, 0, stream>>>(tmp, bbase, row_fill, csr);

        norm_init_csr_k<<<(kN + 3) / 4, 256, 0, stream>>>(f_ego, f_nrm, acc);

        // ---- 4 fused layers: ego -> xa -> xb -> xa -> xb ----
        const float* xin = f_ego;
        float* xout = f_xa;
        for (int l = 0; l < 4; ++l) {
            layer_k<<<(kN + 3) / 4, 256, 0, stream>>>(row_ptr, csr, f_ego, f_nrm,
                                                      xin, xout, acc);
            xin  = xout;
            xout = (xout == f_xa) ? f_xb : f_xa;
        }
    } else {
        // ---- fallback: atomic path ----
        item_ego_k<<<(kNItem + kRowsBlk - 1) / kRowsBlk, 256, 0, stream>>>(
            item_fea, mlp_w, mlp_b, f_ego);
        float* f_x = f_xa;
        float* f_y = f_xb;
        norm_init_full_k<<<(kN + 3) / 4, 256, 0, stream>>>(f_ego, f_nrm, f_x, acc);
        for (int l = 0; l < 4; ++l) {
            hipMemsetAsync(f_y, 0, NE * sizeof(float), stream);
            spmm_k<<<(int)(((long long)kNnz * 64 + 255) / 256), 256, 0, stream>>>(
                adj_rows, adj_cols, adj_vals, f_x, f_y);
            weight_k<<<(kN + 3) / 4, 256, 0, stream>>>(f_ego, f_nrm, f_y, f_x, acc);
        }
    }
}

// Round 4
// 857.680 us; speedup vs baseline: 1.1680x; 1.0143x over previous
//
#include <hip/hip_runtime.h>
#include <hip/hip_fp16.h>

constexpr int kNUser = 100000;
constexpr int kNItem = 50000;
constexpr int kN     = 150000;
constexpr int kEmb   = 64;
constexpr int kFeat  = 384;
constexpr int kNnz   = 2400000;
constexpr float kEps = 1e-8f;

constexpr int kChunk = 1024;                       // elements per scan block
constexpr int kNB    = (kN + kChunk - 1) / kChunk; // 147 scan blocks

// binned-scatter params: 256 buckets of 586 rows; (rowrel<<18)|col packs into
// 28 bits (col < 2^18 = 262144, rowrel < 1024).
constexpr int kNBkt   = 256;
constexpr int kBR     = (kN + kNBkt - 1) / kNBkt;  // 586
constexpr int kChunkA = 4096;                      // edges per bucket_k WG
constexpr int kNWGA   = (kNnz + kChunkA - 1) / kChunkA;  // 586

// item-MLP MFMA geometry: 12 k-steps (K=384/32), 4 n-tiles (N=64/16)
constexpr int kKS     = kFeat / 32;   // 12
constexpr int kNT     = kEmb / 16;    // 4
constexpr int kWElems = kKS * kNT * 64 * 8;  // 24576 pre-split W frag elems

typedef __attribute__((ext_vector_type(8))) short short8v;   // 8 bf16 (4 VGPR)
typedef __attribute__((ext_vector_type(4))) float floatx4;

__device__ inline unsigned short f2bf(float f) {   // fp32 -> bf16 bits, RNE
    unsigned u = __float_as_uint(f);
    return (unsigned short)((u + 0x7FFFu + ((u >> 16) & 1u)) >> 16);
}
__device__ inline float bf2f(unsigned short h) {
    return __uint_as_float((unsigned)h << 16);
}

// ================= shared init kernels =================

__global__ void prompt_sum_k(const float* __restrict__ p, float* __restrict__ out) {
    int d = threadIdx.x;  // 64 threads
    float s = 0.f;
#pragma unroll
    for (int i = 0; i < 8; ++i) s += p[i * kEmb + d];
    out[d] = s;
}

__global__ void user_ego_k(const float* __restrict__ uf, const float* __restrict__ ps,
                           float* __restrict__ ego) {
    int i = blockIdx.x * blockDim.x + threadIdx.x;
    if (i >= kNUser * kEmb) return;
    ego[i] = uf[i] + ps[i & 63];
}

// ---- W pre-split: fragment-ordered bf16 hi/lo. Layout:
// idx = ((ks*kNT + nt)*64 + lane)*8 + j  ->  w[k = ks*32 + (lane>>4)*8 + j]
//                                            [n = nt*16 + (lane&15)]
__global__ void wsplit_k(const float* __restrict__ w, unsigned short* __restrict__ whi,
                         unsigned short* __restrict__ wlo) {
    int t = blockIdx.x * 256 + threadIdx.x;
    if (t >= kWElems) return;
    int j    = t & 7;
    int lane = (t >> 3) & 63;
    int nt   = (t >> 9) & 3;
    int ks   = t >> 11;
    int k = ks * 32 + (lane >> 4) * 8 + j;
    int n = nt * 16 + (lane & 15);
    float v = w[k * kEmb + n];
    unsigned short h = f2bf(v);
    whi[t] = h;
    wlo[t] = f2bf(v - bf2f(h));
}

// ---- item MLP via bf16x2-split MFMA (fp32-equivalent: drops only the
// a_lo*w_lo term, ~2^-18 relative). Wave = 16 rows x 64 cols = 4x
// mfma_f32_16x16x32_bf16 tiles; separate hi/lo accumulator chains.
__global__ __launch_bounds__(256)
void item_ego_mfma_k(const float* __restrict__ itf, const unsigned short* __restrict__ whi,
                     const unsigned short* __restrict__ wlo, const float* __restrict__ b,
                     float* __restrict__ ego) {
    int t    = threadIdx.x;
    int wid  = t >> 6;
    int lane = t & 63;
    int r0   = blockIdx.x * 64 + wid * 16;   // wave's first row
    int arow = r0 + (lane & 15);             // this lane's A row
    int kg   = lane >> 4;                    // k-group 0..3
    bool av  = arow < kNItem;                // uniform per wave (boundary % 16)
    const float* ap = itf + (size_t)(av ? arow : 0) * kFeat + kg * 8;

    const short8v* whv = (const short8v*)whi;
    const short8v* wlv = (const short8v*)wlo;

    floatx4 accH[kNT], accL[kNT];
#pragma unroll
    for (int nt = 0; nt < kNT; ++nt) {
        accH[nt] = (floatx4){0.f, 0.f, 0.f, 0.f};
        accL[nt] = (floatx4){0.f, 0.f, 0.f, 0.f};
    }

    for (int ks = 0; ks < kKS; ++ks) {
        const float4 z = make_float4(0.f, 0.f, 0.f, 0.f);
        float4 a0 = av ? *(const float4*)(ap + ks * 32)     : z;
        float4 a1 = av ? *(const float4*)(ap + ks * 32 + 4) : z;
        short8v ah, al;
#pragma unroll
        for (int j = 0; j < 8; ++j) {
            float f = (j < 4) ? ((const float*)&a0)[j] : ((const float*)&a1)[j - 4];
            unsigned short h = f2bf(f);
            ah[j] = (short)h;
            al[j] = (short)f2bf(f - bf2f(h));
        }
#pragma unroll
        for (int nt = 0; nt < kNT; ++nt) {
            short8v bh = whv[(ks * kNT + nt) * 64 + lane];
            short8v bl = wlv[(ks * kNT + nt) * 64 + lane];
            accH[nt] = __builtin_amdgcn_mfma_f32_16x16x32_bf16(ah, bh, accH[nt], 0, 0, 0);
            accL[nt] = __builtin_amdgcn_mfma_f32_16x16x32_bf16(ah, bl, accL[nt], 0, 0, 0);
            accL[nt] = __builtin_amdgcn_mfma_f32_16x16x32_bf16(al, bh, accL[nt], 0, 0, 0);
        }
    }

    // C/D layout (verified m89/m91): col = lane&15, row = (lane>>4)*4 + reg
    int col0  = lane & 15;
    int rsub  = (lane >> 4) * 4;
#pragma unroll
    for (int nt = 0; nt < kNT; ++nt) {
        float bb = b[nt * 16 + col0];
#pragma unroll
        for (int r = 0; r < 4; ++r) {
            int row = r0 + rsub + r;
            if (row < kNItem)
                ego[(size_t)(kNUser + row) * kEmb + nt * 16 + col0] =
                    tanhf(accH[nt][r] + accL[nt][r] + bb);
        }
    }
}

// ---- fallback-path item MLP (fp32 VALU, LDS-staged) ----
constexpr int kRW      = 16;   // rows per wave
constexpr int kRowsBlk = 64;   // rows per block (4 waves)
constexpr int kKc      = 32;   // K-chunk

__global__ __launch_bounds__(256, 2)
void item_ego_k(const float* __restrict__ itf, const float* __restrict__ w,
                const float* __restrict__ b, float* __restrict__ ego) {
    __shared__ float lds_a[kRowsBlk * kKc];  // 8 KB
    int t      = threadIdx.x;
    int wid    = t >> 6;
    int lane   = t & 63;
    int blk_r0 = blockIdx.x * kRowsBlk;

    float acc[kRW];
#pragma unroll
    for (int r = 0; r < kRW; ++r) acc[r] = 0.f;

    int srow = t >> 3;             // 0..31
    int scol = (t & 7) * 4;        // 0,4,..,28

    for (int kc = 0; kc < kFeat; kc += kKc) {
        __syncthreads();
        {
            const float4 z = make_float4(0.f, 0.f, 0.f, 0.f);
            int gr0 = blk_r0 + srow;
            int gr1 = gr0 + 32;
            float4 v0 = (gr0 < kNItem)
                ? *(const float4*)(itf + (size_t)gr0 * kFeat + kc + scol) : z;
            float4 v1 = (gr1 < kNItem)
                ? *(const float4*)(itf + (size_t)gr1 * kFeat + kc + scol) : z;
            *(float4*)(lds_a + srow * kKc + scol)        = v0;
            *(float4*)(lds_a + (srow + 32) * kKc + scol) = v1;
        }
        float wreg[kKc];
#pragma unroll
        for (int k = 0; k < kKc; ++k) wreg[k] = w[(kc + k) * kEmb + lane];
        __syncthreads();
#pragma unroll
        for (int r = 0; r < kRW; ++r) {
            const float4* av = (const float4*)(lds_a + (wid * kRW + r) * kKc);
#pragma unroll
            for (int q = 0; q < 8; ++q) {
                float4 a = av[q];
                acc[r] = fmaf(a.x, wreg[q * 4 + 0], acc[r]);
                acc[r] = fmaf(a.y, wreg[q * 4 + 1], acc[r]);
                acc[r] = fmaf(a.z, wreg[q * 4 + 2], acc[r]);
                acc[r] = fmaf(a.w, wreg[q * 4 + 3], acc[r]);
            }
        }
    }
    float bv = b[lane];
#pragma unroll
    for (int r = 0; r < kRW; ++r) {
        int row = blk_r0 + wid * kRW + r;
        if (row < kNItem)
            ego[(size_t)(kNUser + row) * kEmb + lane] = tanhf(acc[r] + bv);
    }
}

// nrm + acc init + fp16 shadow of ego (gather source for layer 0)
__global__ void norm_init_csr_k(const float* __restrict__ ego, float* __restrict__ nrm,
                                float* __restrict__ acc, unsigned short* __restrict__ egoh) {
    int wid  = threadIdx.x >> 6;
    int lane = threadIdx.x & 63;
    int row  = blockIdx.x * 4 + wid;
    if (row >= kN) return;
    size_t idx = (size_t)row * kEmb + lane;
    float e = ego[idx];
    acc[idx] = e;
    __half h = __float2half_rn(e);
    egoh[idx] = *(unsigned short*)&h;
    float s = e * e;
#pragma unroll
    for (int o = 32; o >= 1; o >>= 1) s += __shfl_xor(s, o, 64);
    if (lane == 0) nrm[row] = sqrtf(s);
}

// ================= CSR build =================

__global__ void hist_k(const int* __restrict__ rows, int* __restrict__ cnt) {
    int e = blockIdx.x * blockDim.x + threadIdx.x;
    if (e < kNnz) atomicAdd(&cnt[rows[e]], 1);
}

__global__ void scan1_k(const int* __restrict__ cnt, int* __restrict__ excl_out,
                        int* __restrict__ blk_sum) {
    __shared__ int sd[256];
    int b = blockIdx.x, t = threadIdx.x;
    int base = b * kChunk + t * 4;
    int c0 = (base + 0 < kN) ? cnt[base + 0] : 0;
    int c1 = (base + 1 < kN) ? cnt[base + 1] : 0;
    int c2 = (base + 2 < kN) ? cnt[base + 2] : 0;
    int c3 = (base + 3 < kN) ? cnt[base + 3] : 0;
    int tsum = c0 + c1 + c2 + c3;
    sd[t] = tsum;
    __syncthreads();
#pragma unroll
    for (int off = 1; off < 256; off <<= 1) {
        int v = (t >= off) ? sd[t - off] : 0;
        __syncthreads();
        sd[t] += v;
        __syncthreads();
    }
    int excl = sd[t] - tsum;
    if (t == 255) blk_sum[b] = sd[255];
    int run = excl;
    if (base + 0 < kN) { excl_out[base + 0] = run; run += c0; }
    if (base + 1 < kN) { excl_out[base + 1] = run; run += c1; }
    if (base + 2 < kN) { excl_out[base + 2] = run; run += c2; }
    if (base + 3 < kN) { excl_out[base + 3] = run; run += c3; }
}

__global__ void scan2_k(const int* __restrict__ blk_sum, int* __restrict__ blk_off) {
    __shared__ int sd[256];
    int t = threadIdx.x;
    int v = (t < kNB) ? blk_sum[t] : 0;
    sd[t] = v;
    __syncthreads();
#pragma unroll
    for (int off = 1; off < 256; off <<= 1) {
        int u = (t >= off) ? sd[t - off] : 0;
        __syncthreads();
        sd[t] += u;
        __syncthreads();
    }
    if (t < kNB) blk_off[t] = sd[t] - v;
}

__global__ void scan3_k(int* __restrict__ rp, int* __restrict__ rf,
                        const int* __restrict__ blk_off) {
    int b = blockIdx.x, t = threadIdx.x;
    int base = b * kChunk + t * 4;
    int o = blk_off[b];
#pragma unroll
    for (int k = 0; k < 4; ++k) {
        int i = base + k;
        if (i < kN) { int v = rp[i] + o; rp[i] = v; rf[i] = v; }
    }
    if (b == 0 && t == 0) rp[kN] = kNnz;
}

// bucket bases: bbase[b] = row_ptr[min(b*kBR, kN)]; bbase[kNBkt] = kNnz
__global__ void bbase_k(const int* __restrict__ rp, int* __restrict__ bbase) {
    int b = blockIdx.x * blockDim.x + threadIdx.x;
    if (b <= kNBkt) {
        int r = b * kBR;
        bbase[b] = rp[r < kN ? r : kN];
    }
}

// phase A: partition edges into 256 row-range buckets (LDS histogram + one
// global atomicAdd per (WG,bucket) reserving a contiguous run).
__global__ __launch_bounds__(256)
void bucket_k(const int* __restrict__ rows, const int* __restrict__ cols,
              const float* __restrict__ vals, const int* __restrict__ bbase,
              int* __restrict__ bfill, int2* __restrict__ tmp) {
    __shared__ int cnt[kNBkt];
    __shared__ int wgbase[kNBkt];
    int t  = threadIdx.x;
    int e0 = blockIdx.x * kChunkA;
    for (int i = t; i < kNBkt; i += 256) cnt[i] = 0;
    __syncthreads();
    int myb[kChunkA / 256];
    int myoff[kChunkA / 256];
#pragma unroll
    for (int k = 0; k < kChunkA / 256; ++k) {
        int e = e0 + k * 256 + t;                 // coalesced
        if (e < kNnz) {
            int b = rows[e] / kBR;                // const-divisor magic mul
            myb[k]   = b;
            myoff[k] = atomicAdd(&cnt[b], 1);     // LDS atomic
        } else {
            myb[k] = -1;
        }
    }
    __syncthreads();
    for (int i = t; i < kNBkt; i += 256)
        wgbase[i] = cnt[i] ? atomicAdd(&bfill[i], cnt[i]) : 0;
    __syncthreads();
#pragma unroll
    for (int k = 0; k < kChunkA / 256; ++k) {
        int b = myb[k];
        if (b < 0) continue;
        int e = e0 + k * 256 + t;
        int pos = bbase[b] + wgbase[b] + myoff[k];
        int rowrel = rows[e] - b * kBR;           // re-read, L2-hot
        tmp[pos] = make_int2((rowrel << 18) | cols[e], __float_as_int(vals[e]));
    }
}

// phase B: one WG per bucket; sequential reads, final placement via rf atomic.
__global__ __launch_bounds__(256)
void debucket_k(const int2* __restrict__ tmp, const int* __restrict__ bbase,
                int* __restrict__ rf, int2* __restrict__ csr) {
    int b  = blockIdx.x;
    int t  = threadIdx.x;
    int j0 = bbase[b];
    int j1 = bbase[b + 1];
    int rbase = b * kBR;
    for (int jb = j0; jb < j1; jb += 1024) {
        int2 e[4];
        int  pos[4];
        bool v[4];
#pragma unroll
        for (int q = 0; q < 4; ++q) {
            int j = jb + q * 256 + t;
            v[q] = j < j1;
            if (v[q]) e[q] = tmp[j];
        }
#pragma unroll
        for (int q = 0; q < 4; ++q)
            if (v[q]) {
                int row = rbase + (int)((unsigned)e[q].x >> 18);
                pos[q] = atomicAdd(&rf[row], 1);
            }
#pragma unroll
        for (int q = 0; q < 4; ++q)
            if (v[q]) csr[pos[q]] = make_int2(e[q].x & 0x3FFFF, e[q].y);
    }
}

// ============ fused layer: pull-SpMM + cosine reweight + acc ============
// R8: x gathered in fp16 (128 B/row/replica instead of 256 B) to halve the
// XCD-amplified gather traffic (~231 MB -> ~115 MB per layer). acc still
// accumulates fp32 w*s (only the gathered operand is rounded). Last layer
// skips the xout write (nothing gathers it).
__global__ __launch_bounds__(256)
void layer_k(const int* __restrict__ rp, const int2* __restrict__ csr,
             const float* __restrict__ ego, const float* __restrict__ nrm,
             const unsigned short* __restrict__ xin_h,
             unsigned short* __restrict__ xout_h,
             float* __restrict__ acc, int write_x) {
    int wid  = threadIdx.x >> 6;
    int lane = threadIdx.x & 63;
    int row  = blockIdx.x * 4 + wid;
    if (row >= kN) return;
    int q   = lane >> 4;        // edge slot within a group of 4
    int sub = lane & 15;        // dim quad: dims 4*sub .. 4*sub+3
    int p0 = rp[row];
    int p1 = rp[row + 1];

    float4 s = make_float4(0.f, 0.f, 0.f, 0.f);
    for (int base = p0; base < p1; base += 16) {
        int2  e[4];
        float w[4];
#pragma unroll
        for (int g = 0; g < 4; ++g) {
            int j  = base + g * 4 + q;
            bool v = j < p1;
            e[g] = csr[v ? j : p0];          // 16-lane broadcast load, 8 B
            w[g] = v ? __int_as_float(e[g].y) : 0.f;
        }
        uint2 gv[4];
#pragma unroll
        for (int g = 0; g < 4; ++g)
            gv[g] = *(const uint2*)(xin_h + (size_t)e[g].x * kEmb + sub * 4);
#pragma unroll
        for (int g = 0; g < 4; ++g) {
            float2 f0 = __half22float2(*(const __half2*)&gv[g].x);
            float2 f1 = __half22float2(*(const __half2*)&gv[g].y);
            s.x = fmaf(w[g], f0.x, s.x);
            s.y = fmaf(w[g], f0.y, s.y);
            s.z = fmaf(w[g], f1.x, s.z);
            s.w = fmaf(w[g], f1.y, s.w);
        }
    }
    // fold the 4 edge slots
#pragma unroll
    for (int o = 16; o <= 32; o <<= 1) {
        s.x += __shfl_xor(s.x, o, 64);
        s.y += __shfl_xor(s.y, o, 64);
        s.z += __shfl_xor(s.z, o, 64);
        s.w += __shfl_xor(s.w, o, 64);
    }
    size_t idx = (size_t)row * kEmb + sub * 4;
    const float4 ev = *(const float4*)(ego + idx);
    float d = s.x * ev.x + s.y * ev.y + s.z * ev.z + s.w * ev.w;
    float n = s.x * s.x + s.y * s.y + s.z * s.z + s.w * s.w;
#pragma unroll
    for (int o = 1; o <= 8; o <<= 1) {
        d += __shfl_xor(d, o, 64);
        n += __shfl_xor(n, o, 64);
    }
    float wgt = d / fmaxf(sqrtf(n) * nrm[row], kEps);
    if (q == 0) {   // one replica writes; guards acc+= from 4x duplication
        float4 xw = make_float4(wgt * s.x, wgt * s.y, wgt * s.z, wgt * s.w);
        if (write_x) {
            __half2 o0 = __floats2half2_rn(xw.x, xw.y);
            __half2 o1 = __floats2half2_rn(xw.z, xw.w);
            uint2 st;
            st.x = *(unsigned*)&o0;
            st.y = *(unsigned*)&o1;
            *(uint2*)(xout_h + idx) = st;
        }
        float4 av = *(const float4*)(acc + idx);
        av.x += xw.x; av.y += xw.y; av.z += xw.z; av.w += xw.w;
        *(float4*)(acc + idx) = av;
    }
}

// ================= fallback (atomic) kernels =================

__global__ void norm_init_full_k(const float* __restrict__ ego, float* __restrict__ nrm,
                                 float* __restrict__ x, float* __restrict__ acc) {
    int wid  = threadIdx.x >> 6;
    int lane = threadIdx.x & 63;
    int row  = blockIdx.x * 4 + wid;
    if (row >= kN) return;
    size_t idx = (size_t)row * kEmb + lane;
    float e = ego[idx];
    x[idx]   = e;
    acc[idx] = e;
    float s = e * e;
#pragma unroll
    for (int o = 32; o >= 1; o >>= 1) s += __shfl_xor(s, o, 64);
    if (lane == 0) nrm[row] = sqrtf(s);
}

__global__ void spmm_k(const int* __restrict__ rows, const int* __restrict__ cols,
                       const float* __restrict__ vals, const float* __restrict__ x,
                       float* __restrict__ y) {
    long long t = (long long)blockIdx.x * blockDim.x + threadIdx.x;
    int e = (int)(t >> 6);
    if (e >= kNnz) return;
    int lane = threadIdx.x & 63;
    atomicAdd(y + (size_t)rows[e] * kEmb + lane, vals[e] * x[(size_t)cols[e] * kEmb + lane]);
}

__global__ void weight_k(const float* __restrict__ ego, const float* __restrict__ nrm,
                         const float* __restrict__ y, float* __restrict__ x,
                         float* __restrict__ acc) {
    int wid  = threadIdx.x >> 6;
    int lane = threadIdx.x & 63;
    int row  = blockIdx.x * 4 + wid;
    if (row >= kN) return;
    size_t idx = (size_t)row * kEmb + lane;
    float yv = y[idx];
    float ev = ego[idx];
    float d = yv * ev;
    float n = yv * yv;
#pragma unroll
    for (int o = 32; o >= 1; o >>= 1) {
        d += __shfl_xor(d, o, 64);
        n += __shfl_xor(n, o, 64);
    }
    float w  = d / fmaxf(sqrtf(n) * nrm[row], kEps);
    float xw = w * yv;
    x[idx] = xw;
    acc[idx] += xw;
}

// ================= launch =================

extern "C" void kernel_launch(void* const* d_in, const int* in_sizes, int n_in,
                              void* d_out, int out_size, void* d_ws, size_t ws_size,
                              hipStream_t stream) {
    const float* user_fea = (const float*)d_in[0];
    const float* item_fea = (const float*)d_in[1];
    const float* prompt   = (const float*)d_in[2];
    const float* mlp_w    = (const float*)d_in[3];
    const float* mlp_b    = (const float*)d_in[4];
    const int*   adj_rows = (const int*)d_in[5];
    const int*   adj_cols = (const int*)d_in[6];
    const float* adj_vals = (const float*)d_in[7];
    float* acc = (float*)d_out;   // running layer sum accumulates in-place in d_out

    const size_t NE = (size_t)kN * kEmb;  // 9.6M
    float* ws = (float*)d_ws;

    // ---- workspace layout (4-byte units); shared prefix, then CSR-path ----
    size_t off = 0;
    float* f_ego = ws + off; off += NE;
    float* f_ps  = ws + off; off += 64;
    float* f_nrm = ws + off; off += kN;
    size_t branch0 = off;
    // CSR path: fp16 gather buffers
    unsigned short* f_egoh = (unsigned short*)(ws + off); off += NE / 2;
    unsigned short* f_xha  = (unsigned short*)(ws + off); off += NE / 2;  // 19.2 MB
    unsigned short* f_xhb  = (unsigned short*)(ws + off); off += NE / 2;
    int* row_cnt  = (int*)(ws + off); off += kN;
    int* row_ptr  = (int*)(ws + off); off += kN + 1;
    int* row_fill = (int*)(ws + off); off += kN;
    int* blk_sum  = (int*)(ws + off); off += kNB;
    int* blk_off  = (int*)(ws + off); off += kNB;
    int* bbase    = (int*)(ws + off); off += kNBkt + 1;
    int* bfill    = (int*)(ws + off); off += kNBkt;
    off = (off + 3) & ~(size_t)3;                   // 16B-align W frags
    unsigned short* whi = (unsigned short*)(ws + off); off += kWElems / 2;
    unsigned short* wlo = (unsigned short*)(ws + off); off += kWElems / 2;
    off = (off + 1) & ~(size_t)1;                   // 8B-align csr
    int2* csr = (int2*)(ws + off); off += (size_t)kNnz * 2;
    const bool use_csr = ws_size >= off * 4;

    // ---- common init ----
    prompt_sum_k<<<1, 64, 0, stream>>>(prompt, f_ps);
    user_ego_k<<<(kNUser * kEmb + 255) / 256, 256, 0, stream>>>(user_fea, f_ps, f_ego);

    if (use_csr) {
        // item MLP via bf16x2-split MFMA
        wsplit_k<<<(kWElems + 255) / 256, 256, 0, stream>>>(mlp_w, whi, wlo);
        item_ego_mfma_k<<<(kNItem + 63) / 64, 256, 0, stream>>>(item_fea, whi, wlo,
                                                                mlp_b, f_ego);

        // bucket staging aliases f_xha (19.2 MB, free until layer 0 output)
        int2* tmp = (int2*)f_xha;
        // ---- build CSR via 2-phase binned counting sort ----
        hipMemsetAsync(row_cnt, 0, kN * sizeof(int), stream);
        hipMemsetAsync(bfill, 0, kNBkt * sizeof(int), stream);
        hist_k<<<(kNnz + 255) / 256, 256, 0, stream>>>(adj_rows, row_cnt);
        scan1_k<<<kNB, 256, 0, stream>>>(row_cnt, row_ptr, blk_sum);
        scan2_k<<<1, 256, 0, stream>>>(blk_sum, blk_off);
        scan3_k<<<kNB, 256, 0, stream>>>(row_ptr, row_fill, blk_off);
        bbase_k<<<2, 256, 0, stream>>>(row_ptr, bbase);
        bucket_k<<<kNWGA, 256, 0, stream>>>(adj_rows, adj_cols, adj_vals,
                                            bbase, bfill, tmp);
        debucket_k<<<kNBkt, 256, 0, stream>>>(tmp, bbase, row_fill, csr);

        norm_init_csr_k<<<(kN + 3) / 4, 256, 0, stream>>>(f_ego, f_nrm, acc, f_egoh);

        // ---- 4 fused layers: egoh -> xha -> xhb -> xha -> (no write) ----
        const unsigned short* xin = f_egoh;
        unsigned short* xout = f_xha;
        for (int l = 0; l < 4; ++l) {
            layer_k<<<(kN + 3) / 4, 256, 0, stream>>>(row_ptr, csr, f_ego, f_nrm,
                                                      xin, xout, acc, (l < 3) ? 1 : 0);
            xin  = xout;
            xout = (xout == f_xha) ? f_xhb : f_xha;
        }
    } else {
        // ---- fallback: atomic path (fp32 buffers carved past shared prefix) ----
        float* f_x = ws + branch0;
        float* f_y = f_x + NE;
        item_ego_k<<<(kNItem + kRowsBlk - 1) / kRowsBlk, 256, 0, stream>>>(
            item_fea, mlp_w, mlp_b, f_ego);
        norm_init_full_k<<<(kN + 3) / 4, 256, 0, stream>>>(f_ego, f_nrm, f_x, acc);
        for (int l = 0; l < 4; ++l) {
            hipMemsetAsync(f_y, 0, NE * sizeof(float), stream);
            spmm_k<<<(int)(((long long)kNnz * 64 + 255) / 256), 256, 0, stream>>>(
                adj_rows, adj_cols, adj_vals, f_x, f_y);
            weight_k<<<(kN + 3) / 4, 256, 0, stream>>>(f_ego, f_nrm, f_y, f_x, acc);
        }
    }
}

// Round 6
// 711.058 us; speedup vs baseline: 1.4088x; 1.2062x over previous
//
#include <hip/hip_runtime.h>
#include <hip/hip_fp16.h>

constexpr int kNUser = 100000;
constexpr int kNItem = 50000;
constexpr int kN     = 150000;
constexpr int kEmb   = 64;
constexpr int kFeat  = 384;
constexpr int kNnz   = 2400000;
constexpr float kEps = 1e-8f;

// binned CSR build: 256 buckets of 586 rows; (rowrel<<18)|col packs into
// 28 bits (col < 2^18 = 262144, rowrel < 1024).
constexpr int kNBkt   = 256;
constexpr int kBR     = (kN + kNBkt - 1) / kNBkt;  // 586
constexpr int kChunkA = 4096;                      // edges per bucket WG
constexpr int kNWGA   = (kNnz + kChunkA - 1) / kChunkA;  // 586

// item-MLP MFMA geometry: 12 k-steps (K=384/32), 4 n-tiles (N=64/16)
constexpr int kKS     = kFeat / 32;   // 12
constexpr int kNT     = kEmb / 16;    // 4
constexpr int kWElems = kKS * kNT * 64 * 8;  // 24576 pre-split W frag elems

typedef __attribute__((ext_vector_type(8))) short short8v;   // 8 bf16 (4 VGPR)
typedef __attribute__((ext_vector_type(4))) float floatx4;

__device__ inline unsigned short f2bf(float f) {   // fp32 -> bf16 bits, RNE
    unsigned u = __float_as_uint(f);
    return (unsigned short)((u + 0x7FFFu + ((u >> 16) & 1u)) >> 16);
}
__device__ inline float bf2f(unsigned short h) {
    return __uint_as_float((unsigned)h << 16);
}

// ================= shared init kernels =================

__global__ void prompt_sum_k(const float* __restrict__ p, float* __restrict__ out) {
    int d = threadIdx.x;  // 64 threads
    float s = 0.f;
#pragma unroll
    for (int i = 0; i < 8; ++i) s += p[i * kEmb + d];
    out[d] = s;
}

__global__ void user_ego_k(const float* __restrict__ uf, const float* __restrict__ ps,
                           float* __restrict__ ego) {
    int i = blockIdx.x * blockDim.x + threadIdx.x;
    if (i >= kNUser * kEmb) return;
    ego[i] = uf[i] + ps[i & 63];
}

// ---- W pre-split: fragment-ordered bf16 hi/lo ----
__global__ void wsplit_k(const float* __restrict__ w, unsigned short* __restrict__ whi,
                         unsigned short* __restrict__ wlo) {
    int t = blockIdx.x * 256 + threadIdx.x;
    if (t >= kWElems) return;
    int j    = t & 7;
    int lane = (t >> 3) & 63;
    int nt   = (t >> 9) & 3;
    int ks   = t >> 11;
    int k = ks * 32 + (lane >> 4) * 8 + j;
    int n = nt * 16 + (lane & 15);
    float v = w[k * kEmb + n];
    unsigned short h = f2bf(v);
    whi[t] = h;
    wlo[t] = f2bf(v - bf2f(h));
}

// ---- item MLP via bf16x2-split MFMA (fp32-equivalent) ----
__global__ __launch_bounds__(256)
void item_ego_mfma_k(const float* __restrict__ itf, const unsigned short* __restrict__ whi,
                     const unsigned short* __restrict__ wlo, const float* __restrict__ b,
                     float* __restrict__ ego) {
    int t    = threadIdx.x;
    int wid  = t >> 6;
    int lane = t & 63;
    int r0   = blockIdx.x * 64 + wid * 16;   // wave's first row
    int arow = r0 + (lane & 15);             // this lane's A row
    int kg   = lane >> 4;                    // k-group 0..3
    bool av  = arow < kNItem;                // uniform per wave (boundary % 16)
    const float* ap = itf + (size_t)(av ? arow : 0) * kFeat + kg * 8;

    const short8v* whv = (const short8v*)whi;
    const short8v* wlv = (const short8v*)wlo;

    floatx4 accH[kNT], accL[kNT];
#pragma unroll
    for (int nt = 0; nt < kNT; ++nt) {
        accH[nt] = (floatx4){0.f, 0.f, 0.f, 0.f};
        accL[nt] = (floatx4){0.f, 0.f, 0.f, 0.f};
    }

    for (int ks = 0; ks < kKS; ++ks) {
        const float4 z = make_float4(0.f, 0.f, 0.f, 0.f);
        float4 a0 = av ? *(const float4*)(ap + ks * 32)     : z;
        float4 a1 = av ? *(const float4*)(ap + ks * 32 + 4) : z;
        short8v ah, al;
#pragma unroll
        for (int j = 0; j < 8; ++j) {
            float f = (j < 4) ? ((const float*)&a0)[j] : ((const float*)&a1)[j - 4];
            unsigned short h = f2bf(f);
            ah[j] = (short)h;
            al[j] = (short)f2bf(f - bf2f(h));
        }
#pragma unroll
        for (int nt = 0; nt < kNT; ++nt) {
            short8v bh = whv[(ks * kNT + nt) * 64 + lane];
            short8v bl = wlv[(ks * kNT + nt) * 64 + lane];
            accH[nt] = __builtin_amdgcn_mfma_f32_16x16x32_bf16(ah, bh, accH[nt], 0, 0, 0);
            accL[nt] = __builtin_amdgcn_mfma_f32_16x16x32_bf16(ah, bl, accL[nt], 0, 0, 0);
            accL[nt] = __builtin_amdgcn_mfma_f32_16x16x32_bf16(al, bh, accL[nt], 0, 0, 0);
        }
    }

    // C/D layout (verified m89/m91): col = lane&15, row = (lane>>4)*4 + reg
    int col0  = lane & 15;
    int rsub  = (lane >> 4) * 4;
#pragma unroll
    for (int nt = 0; nt < kNT; ++nt) {
        float bb = b[nt * 16 + col0];
#pragma unroll
        for (int r = 0; r < 4; ++r) {
            int row = r0 + rsub + r;
            if (row < kNItem)
                ego[(size_t)(kNUser + row) * kEmb + nt * 16 + col0] =
                    tanhf(accH[nt][r] + accL[nt][r] + bb);
        }
    }
}

// ---- fallback-path item MLP (fp32 VALU, LDS-staged) ----
constexpr int kRW      = 16;   // rows per wave
constexpr int kRowsBlk = 64;   // rows per block (4 waves)
constexpr int kKc      = 32;   // K-chunk

__global__ __launch_bounds__(256, 2)
void item_ego_k(const float* __restrict__ itf, const float* __restrict__ w,
                const float* __restrict__ b, float* __restrict__ ego) {
    __shared__ float lds_a[kRowsBlk * kKc];  // 8 KB
    int t      = threadIdx.x;
    int wid    = t >> 6;
    int lane   = t & 63;
    int blk_r0 = blockIdx.x * kRowsBlk;

    float acc[kRW];
#pragma unroll
    for (int r = 0; r < kRW; ++r) acc[r] = 0.f;

    int srow = t >> 3;             // 0..31
    int scol = (t & 7) * 4;        // 0,4,..,28

    for (int kc = 0; kc < kFeat; kc += kKc) {
        __syncthreads();
        {
            const float4 z = make_float4(0.f, 0.f, 0.f, 0.f);
            int gr0 = blk_r0 + srow;
            int gr1 = gr0 + 32;
            float4 v0 = (gr0 < kNItem)
                ? *(const float4*)(itf + (size_t)gr0 * kFeat + kc + scol) : z;
            float4 v1 = (gr1 < kNItem)
                ? *(const float4*)(itf + (size_t)gr1 * kFeat + kc + scol) : z;
            *(float4*)(lds_a + srow * kKc + scol)        = v0;
            *(float4*)(lds_a + (srow + 32) * kKc + scol) = v1;
        }
        float wreg[kKc];
#pragma unroll
        for (int k = 0; k < kKc; ++k) wreg[k] = w[(kc + k) * kEmb + lane];
        __syncthreads();
#pragma unroll
        for (int r = 0; r < kRW; ++r) {
            const float4* av = (const float4*)(lds_a + (wid * kRW + r) * kKc);
#pragma unroll
            for (int q = 0; q < 8; ++q) {
                float4 a = av[q];
                acc[r] = fmaf(a.x, wreg[q * 4 + 0], acc[r]);
                acc[r] = fmaf(a.y, wreg[q * 4 + 1], acc[r]);
                acc[r] = fmaf(a.z, wreg[q * 4 + 2], acc[r]);
                acc[r] = fmaf(a.w, wreg[q * 4 + 3], acc[r]);
            }
        }
    }
    float bv = b[lane];
#pragma unroll
    for (int r = 0; r < kRW; ++r) {
        int row = blk_r0 + wid * kRW + r;
        if (row < kNItem)
            ego[(size_t)(kNUser + row) * kEmb + lane] = tanhf(acc[r] + bv);
    }
}

// nrm + fp16 shadow of ego (gather source for layer 0). acc is no longer
// written here: the last layer_k composes acc = ego + x1 + x2 + x3 + x4.
__global__ void norm_init_csr_k(const float* __restrict__ ego, float* __restrict__ nrm,
                                unsigned short* __restrict__ egoh) {
    int wid  = threadIdx.x >> 6;
    int lane = threadIdx.x & 63;
    int row  = blockIdx.x * 4 + wid;
    if (row >= kN) return;
    size_t idx = (size_t)row * kEmb + lane;
    float e = ego[idx];
    __half h = __float2half_rn(e);
    egoh[idx] = *(unsigned short*)&h;
    float s = e * e;
#pragma unroll
    for (int o = 32; o >= 1; o >>= 1) s += __shfl_xor(s, o, 64);
    if (lane == 0) nrm[row] = sqrtf(s);
}

// ================= CSR build (bucket counting sort, no global row atomics) =================

// 256-bin bucket histogram, LDS-aggregated (150K global atomics total)
__global__ __launch_bounds__(256)
void bcnt_k(const int* __restrict__ rows, int* __restrict__ bcnt) {
    __shared__ int cnt[kNBkt];
    int t  = threadIdx.x;
    int e0 = blockIdx.x * kChunkA;
    for (int i = t; i < kNBkt; i += 256) cnt[i] = 0;
    __syncthreads();
#pragma unroll
    for (int k = 0; k < kChunkA / 256; ++k) {
        int e = e0 + k * 256 + t;
        if (e < kNnz) atomicAdd(&cnt[rows[e] / kBR], 1);
    }
    __syncthreads();
    for (int i = t; i < kNBkt; i += 256)
        if (cnt[i]) atomicAdd(&bcnt[i], cnt[i]);
}

// exclusive scan of the 256 bucket counts -> bbase; also zeroes bfill
__global__ void bscan_k(const int* __restrict__ bcnt, int* __restrict__ bbase,
                        int* __restrict__ bfill) {
    __shared__ int sd[kNBkt];
    int t = threadIdx.x;
    int v = bcnt[t];
    sd[t] = v;
    __syncthreads();
#pragma unroll
    for (int off = 1; off < kNBkt; off <<= 1) {
        int u = (t >= off) ? sd[t - off] : 0;
        __syncthreads();
        sd[t] += u;
        __syncthreads();
    }
    bbase[t] = sd[t] - v;
    if (t == kNBkt - 1) bbase[kNBkt] = kNnz;
    bfill[t] = 0;
}

// phase A: partition edges into 256 row-range buckets (LDS histogram + one
// global atomicAdd per (WG,bucket) reserving a contiguous run).
__global__ __launch_bounds__(256)
void bucket_k(const int* __restrict__ rows, const int* __restrict__ cols,
              const float* __restrict__ vals, const int* __restrict__ bbase,
              int* __restrict__ bfill, int2* __restrict__ tmp) {
    __shared__ int cnt[kNBkt];
    __shared__ int wgbase[kNBkt];
    int t  = threadIdx.x;
    int e0 = blockIdx.x * kChunkA;
    for (int i = t; i < kNBkt; i += 256) cnt[i] = 0;
    __syncthreads();
    int myb[kChunkA / 256];
    int myoff[kChunkA / 256];
#pragma unroll
    for (int k = 0; k < kChunkA / 256; ++k) {
        int e = e0 + k * 256 + t;                 // coalesced
        if (e < kNnz) {
            int b = rows[e] / kBR;                // const-divisor magic mul
            myb[k]   = b;
            myoff[k] = atomicAdd(&cnt[b], 1);     // LDS atomic
        } else {
            myb[k] = -1;
        }
    }
    __syncthreads();
    for (int i = t; i < kNBkt; i += 256)
        wgbase[i] = cnt[i] ? atomicAdd(&bfill[i], cnt[i]) : 0;
    __syncthreads();
#pragma unroll
    for (int k = 0; k < kChunkA / 256; ++k) {
        int b = myb[k];
        if (b < 0) continue;
        int e = e0 + k * 256 + t;
        int pos = bbase[b] + wgbase[b] + myoff[k];
        int rowrel = rows[e] - b * kBR;           // re-read, L2-hot
        tmp[pos] = make_int2((rowrel << 18) | cols[e], __float_as_int(vals[e]));
    }
}

// phase B: one WG per bucket. Counts its 586 rows in LDS, scans them in LDS,
// writes row_ptr coalesced, then places edges via LDS-atomic fill into the
// L2-resident csr window. Zero global atomics.
__global__ __launch_bounds__(256)
void debucket2_k(const int2* __restrict__ tmp, const int* __restrict__ bbase,
                 int* __restrict__ rp, int2* __restrict__ csr) {
    __shared__ int rcnt[kBR];
    __shared__ int rbaseL[kBR];
    __shared__ int sd[256];
    int b  = blockIdx.x;
    int t  = threadIdx.x;
    int j0 = bbase[b];
    int j1 = bbase[b + 1];
    for (int i = t; i < kBR; i += 256) rcnt[i] = 0;
    __syncthreads();
    // pass 1: row histogram within bucket
    for (int j = j0 + t; j < j1; j += 256)
        atomicAdd(&rcnt[(unsigned)tmp[j].x >> 18], 1);
    __syncthreads();
    // scan 586 row counts: thread t owns elements [3t, 3t+3)
    int base = t * 3;
    int c0 = (base     < kBR) ? rcnt[base]     : 0;
    int c1 = (base + 1 < kBR) ? rcnt[base + 1] : 0;
    int c2 = (base + 2 < kBR) ? rcnt[base + 2] : 0;
    int tsum = c0 + c1 + c2;
    sd[t] = tsum;
    __syncthreads();
#pragma unroll
    for (int off = 1; off < 256; off <<= 1) {
        int u = (t >= off) ? sd[t - off] : 0;
        __syncthreads();
        sd[t] += u;
        __syncthreads();
    }
    int g0 = j0 + sd[t] - tsum;
    if (base     < kBR) rbaseL[base]     = g0;
    if (base + 1 < kBR) rbaseL[base + 1] = g0 + c0;
    if (base + 2 < kBR) rbaseL[base + 2] = g0 + c0 + c1;
    __syncthreads();
    // row_ptr out (coalesced)
    int rbaseG = b * kBR;
    for (int i = t; i < kBR; i += 256) {
        int r = rbaseG + i;
        if (r < kN) rp[r] = rbaseL[i];
    }
    if (b == kNBkt - 1 && t == 0) rp[kN] = kNnz;
    // reset counters for fill pass
    for (int i = t; i < kBR; i += 256) rcnt[i] = 0;
    __syncthreads();
    // pass 2: place edges (tmp window is L2-hot from pass 1)
    for (int j = j0 + t; j < j1; j += 256) {
        int2 e = tmp[j];
        int rr = (unsigned)e.x >> 18;
        int pos = rbaseL[rr] + atomicAdd(&rcnt[rr], 1);
        csr[pos] = make_int2(e.x & 0x3FFFF, e.y);
    }
}

// ============ fused layer: pull-SpMM + cosine reweight ============
// R9: acc deferred. Mid layers write only fp16 xout (needed for the next
// gather anyway). The LAST layer composes acc = ego + x1 + x2 + x3 + x4 in
// its epilogue (ev = ego row already in registers from the cosine), removing
// 76.8 MB/layer of acc read+write traffic.
__global__ __launch_bounds__(256)
void layer_k(const int* __restrict__ rp, const int2* __restrict__ csr,
             const float* __restrict__ ego, const float* __restrict__ nrm,
             const unsigned short* __restrict__ xin_h,
             unsigned short* __restrict__ xout_h,
             const unsigned short* __restrict__ xh1,
             const unsigned short* __restrict__ xh2,
             float* __restrict__ acc, int last) {
    int wid  = threadIdx.x >> 6;
    int lane = threadIdx.x & 63;
    int row  = blockIdx.x * 4 + wid;
    if (row >= kN) return;
    int q   = lane >> 4;        // edge slot within a group of 4
    int sub = lane & 15;        // dim quad: dims 4*sub .. 4*sub+3
    int p0 = rp[row];
    int p1 = rp[row + 1];

    float4 s = make_float4(0.f, 0.f, 0.f, 0.f);
    for (int base = p0; base < p1; base += 16) {
        int2  e[4];
        float w[4];
#pragma unroll
        for (int g = 0; g < 4; ++g) {
            int j  = base + g * 4 + q;
            bool v = j < p1;
            e[g] = csr[v ? j : p0];          // 16-lane broadcast load, 8 B
            w[g] = v ? __int_as_float(e[g].y) : 0.f;
        }
        uint2 gv[4];
#pragma unroll
        for (int g = 0; g < 4; ++g)
            gv[g] = *(const uint2*)(xin_h + (size_t)e[g].x * kEmb + sub * 4);
#pragma unroll
        for (int g = 0; g < 4; ++g) {
            float2 f0 = __half22float2(*(const __half2*)&gv[g].x);
            float2 f1 = __half22float2(*(const __half2*)&gv[g].y);
            s.x = fmaf(w[g], f0.x, s.x);
            s.y = fmaf(w[g], f0.y, s.y);
            s.z = fmaf(w[g], f1.x, s.z);
            s.w = fmaf(w[g], f1.y, s.w);
        }
    }
    // fold the 4 edge slots
#pragma unroll
    for (int o = 16; o <= 32; o <<= 1) {
        s.x += __shfl_xor(s.x, o, 64);
        s.y += __shfl_xor(s.y, o, 64);
        s.z += __shfl_xor(s.z, o, 64);
        s.w += __shfl_xor(s.w, o, 64);
    }
    size_t idx = (size_t)row * kEmb + sub * 4;
    const float4 ev = *(const float4*)(ego + idx);
    float d = s.x * ev.x + s.y * ev.y + s.z * ev.z + s.w * ev.w;
    float n = s.x * s.x + s.y * s.y + s.z * s.z + s.w * s.w;
#pragma unroll
    for (int o = 1; o <= 8; o <<= 1) {
        d += __shfl_xor(d, o, 64);
        n += __shfl_xor(n, o, 64);
    }
    float wgt = d / fmaxf(sqrtf(n) * nrm[row], kEps);
    if (q == 0) {   // one replica writes
        float4 xw = make_float4(wgt * s.x, wgt * s.y, wgt * s.z, wgt * s.w);
        if (!last) {
            __half2 o0 = __floats2half2_rn(xw.x, xw.y);
            __half2 o1 = __floats2half2_rn(xw.z, xw.w);
            uint2 st;
            st.x = *(unsigned*)&o0;
            st.y = *(unsigned*)&o1;
            *(uint2*)(xout_h + idx) = st;
        } else {
            // acc = ego + x1 + x2 + x3 + x4  (x3 == this layer's xin)
            uint2 a1 = *(const uint2*)(xh1 + idx);
            uint2 a2 = *(const uint2*)(xh2 + idx);
            uint2 a3 = *(const uint2*)(xin_h + idx);
            float2 f1a = __half22float2(*(const __half2*)&a1.x);
            float2 f1b = __half22float2(*(const __half2*)&a1.y);
            float2 f2a = __half22float2(*(const __half2*)&a2.x);
            float2 f2b = __half22float2(*(const __half2*)&a2.y);
            float2 f3a = __half22float2(*(const __half2*)&a3.x);
            float2 f3b = __half22float2(*(const __half2*)&a3.y);
            float4 out;
            out.x = ev.x + f1a.x + f2a.x + f3a.x + xw.x;
            out.y = ev.y + f1a.y + f2a.y + f3a.y + xw.y;
            out.z = ev.z + f1b.x + f2b.x + f3b.x + xw.z;
            out.w = ev.w + f1b.y + f2b.y + f3b.y + xw.w;
            *(float4*)(acc + idx) = out;
        }
    }
}

// ================= fallback (atomic) kernels =================

__global__ void norm_init_full_k(const float* __restrict__ ego, float* __restrict__ nrm,
                                 float* __restrict__ x, float* __restrict__ acc) {
    int wid  = threadIdx.x >> 6;
    int lane = threadIdx.x & 63;
    int row  = blockIdx.x * 4 + wid;
    if (row >= kN) return;
    size_t idx = (size_t)row * kEmb + lane;
    float e = ego[idx];
    x[idx]   = e;
    acc[idx] = e;
    float s = e * e;
#pragma unroll
    for (int o = 32; o >= 1; o >>= 1) s += __shfl_xor(s, o, 64);
    if (lane == 0) nrm[row] = sqrtf(s);
}

__global__ void spmm_k(const int* __restrict__ rows, const int* __restrict__ cols,
                       const float* __restrict__ vals, const float* __restrict__ x,
                       float* __restrict__ y) {
    long long t = (long long)blockIdx.x * blockDim.x + threadIdx.x;
    int e = (int)(t >> 6);
    if (e >= kNnz) return;
    int lane = threadIdx.x & 63;
    atomicAdd(y + (size_t)rows[e] * kEmb + lane, vals[e] * x[(size_t)cols[e] * kEmb + lane]);
}

__global__ void weight_k(const float* __restrict__ ego, const float* __restrict__ nrm,
                         const float* __restrict__ y, float* __restrict__ x,
                         float* __restrict__ acc) {
    int wid  = threadIdx.x >> 6;
    int lane = threadIdx.x & 63;
    int row  = blockIdx.x * 4 + wid;
    if (row >= kN) return;
    size_t idx = (size_t)row * kEmb + lane;
    float yv = y[idx];
    float ev = ego[idx];
    float d = yv * ev;
    float n = yv * yv;
#pragma unroll
    for (int o = 32; o >= 1; o >>= 1) {
        d += __shfl_xor(d, o, 64);
        n += __shfl_xor(n, o, 64);
    }
    float w  = d / fmaxf(sqrtf(n) * nrm[row], kEps);
    float xw = w * yv;
    x[idx] = xw;
    acc[idx] += xw;
}

// ================= launch =================

extern "C" void kernel_launch(void* const* d_in, const int* in_sizes, int n_in,
                              void* d_out, int out_size, void* d_ws, size_t ws_size,
                              hipStream_t stream) {
    const float* user_fea = (const float*)d_in[0];
    const float* item_fea = (const float*)d_in[1];
    const float* prompt   = (const float*)d_in[2];
    const float* mlp_w    = (const float*)d_in[3];
    const float* mlp_b    = (const float*)d_in[4];
    const int*   adj_rows = (const int*)d_in[5];
    const int*   adj_cols = (const int*)d_in[6];
    const float* adj_vals = (const float*)d_in[7];
    float* acc = (float*)d_out;   // written once, by the last layer

    const size_t NE = (size_t)kN * kEmb;  // 9.6M
    float* ws = (float*)d_ws;

    // ---- workspace layout (4-byte units); shared prefix, then CSR-path ----
    size_t off = 0;
    float* f_ego = ws + off; off += NE;
    float* f_ps  = ws + off; off += 64;
    float* f_nrm = ws + off; off += kN;
    size_t branch0 = off;
    // CSR path: fp16 gather buffers (xh1 doubles as bucket tmp)
    unsigned short* f_egoh = (unsigned short*)(ws + off); off += NE / 2;
    unsigned short* f_xh1  = (unsigned short*)(ws + off); off += NE / 2;
    unsigned short* f_xh2  = (unsigned short*)(ws + off); off += NE / 2;
    unsigned short* f_xh3  = (unsigned short*)(ws + off); off += NE / 2;
    int* row_ptr = (int*)(ws + off); off += kN + 1;
    int* bcnt    = (int*)(ws + off); off += kNBkt;
    int* bbase   = (int*)(ws + off); off += kNBkt + 1;
    int* bfill   = (int*)(ws + off); off += kNBkt;
    off = (off + 3) & ~(size_t)3;                   // 16B-align W frags
    unsigned short* whi = (unsigned short*)(ws + off); off += kWElems / 2;
    unsigned short* wlo = (unsigned short*)(ws + off); off += kWElems / 2;
    off = (off + 1) & ~(size_t)1;                   // 8B-align csr
    int2* csr = (int2*)(ws + off); off += (size_t)kNnz * 2;
    const bool use_csr = ws_size >= off * 4;

    // ---- common init ----
    prompt_sum_k<<<1, 64, 0, stream>>>(prompt, f_ps);
    user_ego_k<<<(kNUser * kEmb + 255) / 256, 256, 0, stream>>>(user_fea, f_ps, f_ego);

    if (use_csr) {
        // item MLP via bf16x2-split MFMA
        wsplit_k<<<(kWElems + 255) / 256, 256, 0, stream>>>(mlp_w, whi, wlo);
        item_ego_mfma_k<<<(kNItem + 63) / 64, 256, 0, stream>>>(item_fea, whi, wlo,
                                                                mlp_b, f_ego);

        // bucket staging aliases f_xh1 (free until layer 0 output)
        int2* tmp = (int2*)f_xh1;
        // ---- build CSR via bucket counting sort (no global row atomics) ----
        hipMemsetAsync(bcnt, 0, kNBkt * sizeof(int), stream);
        bcnt_k<<<kNWGA, 256, 0, stream>>>(adj_rows, bcnt);
        bscan_k<<<1, kNBkt, 0, stream>>>(bcnt, bbase, bfill);
        bucket_k<<<kNWGA, 256, 0, stream>>>(adj_rows, adj_cols, adj_vals,
                                            bbase, bfill, tmp);
        debucket2_k<<<kNBkt, 256, 0, stream>>>(tmp, bbase, row_ptr, csr);

        norm_init_csr_k<<<(kN + 3) / 4, 256, 0, stream>>>(f_ego, f_nrm, f_egoh);

        // ---- 4 fused layers: egoh -> xh1 -> xh2 -> xh3 -> acc ----
        layer_k<<<(kN + 3) / 4, 256, 0, stream>>>(row_ptr, csr, f_ego, f_nrm,
                                                  f_egoh, f_xh1, nullptr, nullptr,
                                                  acc, 0);
        layer_k<<<(kN + 3) / 4, 256, 0, stream>>>(row_ptr, csr, f_ego, f_nrm,
                                                  f_xh1, f_xh2, nullptr, nullptr,
                                                  acc, 0);
        layer_k<<<(kN + 3) / 4, 256, 0, stream>>>(row_ptr, csr, f_ego, f_nrm,
                                                  f_xh2, f_xh3, nullptr, nullptr,
                                                  acc, 0);
        layer_k<<<(kN + 3) / 4, 256, 0, stream>>>(row_ptr, csr, f_ego, f_nrm,
                                                  f_xh3, nullptr, f_xh1, f_xh2,
                                                  acc, 1);
    } else {
        // ---- fallback: atomic path (fp32 buffers carved past shared prefix) ----
        float* f_x = ws + branch0;
        float* f_y = f_x + NE;
        item_ego_k<<<(kNItem + kRowsBlk - 1) / kRowsBlk, 256, 0, stream>>>(
            item_fea, mlp_w, mlp_b, f_ego);
        norm_init_full_k<<<(kN + 3) / 4, 256, 0, stream>>>(f_ego, f_nrm, f_x, acc);
        for (int l = 0; l < 4; ++l) {
            hipMemsetAsync(f_y, 0, NE * sizeof(float), stream);
            spmm_k<<<(int)(((long long)kNnz * 64 + 255) / 256), 256, 0, stream>>>(
                adj_rows, adj_cols, adj_vals, f_x, f_y);
            weight_k<<<(kN + 3) / 4, 256, 0, stream>>>(f_ego, f_nrm, f_y, f_x, acc);
        }
    }
}

// Round 8
// 687.682 us; speedup vs baseline: 1.4567x; 1.0340x over previous
//
#include <hip/hip_runtime.h>
#include <hip/hip_fp16.h>

constexpr int kNUser = 100000;
constexpr int kNItem = 50000;
constexpr int kN     = 150000;
constexpr int kEmb   = 64;
constexpr int kFeat  = 384;
constexpr int kNnz   = 2400000;
constexpr float kEps = 1e-8f;

// binned CSR build: 256 buckets of 586 rows; (rowrel<<18)|col packs into
// 28 bits (col < 2^18 = 262144, rowrel < 1024).
constexpr int kNBkt   = 256;
constexpr int kBR     = (kN + kNBkt - 1) / kNBkt;  // 586
constexpr int kChunkA = 4096;                      // edges per bucket WG
constexpr int kNWGA   = (kNnz + kChunkA - 1) / kChunkA;  // 586

// item-MLP MFMA geometry: 12 k-steps (K=384/32), 4 n-tiles (N=64/16)
constexpr int kKS     = kFeat / 32;   // 12
constexpr int kNT     = kEmb / 16;    // 4
constexpr int kWElems = kKS * kNT * 64 * 8;  // 24576 pre-split W frag elems

typedef __attribute__((ext_vector_type(8))) short short8v;   // 8 bf16 (4 VGPR)
typedef __attribute__((ext_vector_type(4))) float floatx4;

__device__ inline unsigned short f2bf(float f) {   // fp32 -> bf16 bits, RNE
    unsigned u = __float_as_uint(f);
    return (unsigned short)((u + 0x7FFFu + ((u >> 16) & 1u)) >> 16);
}
__device__ inline float bf2f(unsigned short h) {
    return __uint_as_float((unsigned)h << 16);
}

// ================= shared init kernels =================

__global__ void prompt_sum_k(const float* __restrict__ p, float* __restrict__ out) {
    int d = threadIdx.x;  // 64 threads
    float s = 0.f;
#pragma unroll
    for (int i = 0; i < 8; ++i) s += p[i * kEmb + d];
    out[d] = s;
}

// fp32-ego variant (fallback path only)
__global__ void user_ego_k(const float* __restrict__ uf, const float* __restrict__ ps,
                           float* __restrict__ ego) {
    int i = blockIdx.x * blockDim.x + threadIdx.x;
    if (i >= kNUser * kEmb) return;
    ego[i] = uf[i] + ps[i & 63];
}

// R10: user rows -> egoh (fp16) + nrm directly; no fp32 ego buffer.
__global__ void user_egoh_k(const float* __restrict__ uf, const float* __restrict__ ps,
                            unsigned short* __restrict__ egoh, float* __restrict__ nrm) {
    int wid  = threadIdx.x >> 6;
    int lane = threadIdx.x & 63;
    int row  = blockIdx.x * 4 + wid;
    if (row >= kNUser) return;
    size_t idx = (size_t)row * kEmb + lane;
    float e = uf[idx] + ps[lane];
    __half h = __float2half_rn(e);
    egoh[idx] = *(unsigned short*)&h;
    float s = e * e;
#pragma unroll
    for (int o = 32; o >= 1; o >>= 1) s += __shfl_xor(s, o, 64);
    if (lane == 0) nrm[row] = sqrtf(s);
}

// ---- W pre-split: fragment-ordered bf16 hi/lo ----
__global__ void wsplit_k(const float* __restrict__ w, unsigned short* __restrict__ whi,
                         unsigned short* __restrict__ wlo) {
    int t = blockIdx.x * 256 + threadIdx.x;
    if (t >= kWElems) return;
    int j    = t & 7;
    int lane = (t >> 3) & 63;
    int nt   = (t >> 9) & 3;
    int ks   = t >> 11;
    int k = ks * 32 + (lane >> 4) * 8 + j;
    int n = nt * 16 + (lane & 15);
    float v = w[k * kEmb + n];
    unsigned short h = f2bf(v);
    whi[t] = h;
    wlo[t] = f2bf(v - bf2f(h));
}

// ---- item MLP via bf16x2-split MFMA; epilogue writes fp16 egoh + nrm
// (norm computed in-register: per-row sum-sq via 4-step shfl_xor over the
// 16-lane column group; C/D layout col=lane&15, row=(lane>>4)*4+reg).
__global__ __launch_bounds__(256)
void item_ego_mfma_k(const float* __restrict__ itf, const unsigned short* __restrict__ whi,
                     const unsigned short* __restrict__ wlo, const float* __restrict__ b,
                     unsigned short* __restrict__ egoh, float* __restrict__ nrm) {
    int t    = threadIdx.x;
    int wid  = t >> 6;
    int lane = t & 63;
    int r0   = blockIdx.x * 64 + wid * 16;   // wave's first row
    int arow = r0 + (lane & 15);             // this lane's A row
    int kg   = lane >> 4;                    // k-group 0..3
    bool av  = arow < kNItem;                // uniform per wave (boundary % 16)
    const float* ap = itf + (size_t)(av ? arow : 0) * kFeat + kg * 8;

    const short8v* whv = (const short8v*)whi;
    const short8v* wlv = (const short8v*)wlo;

    floatx4 accH[kNT], accL[kNT];
#pragma unroll
    for (int nt = 0; nt < kNT; ++nt) {
        accH[nt] = (floatx4){0.f, 0.f, 0.f, 0.f};
        accL[nt] = (floatx4){0.f, 0.f, 0.f, 0.f};
    }

    for (int ks = 0; ks < kKS; ++ks) {
        const float4 z = make_float4(0.f, 0.f, 0.f, 0.f);
        float4 a0 = av ? *(const float4*)(ap + ks * 32)     : z;
        float4 a1 = av ? *(const float4*)(ap + ks * 32 + 4) : z;
        short8v ah, al;
#pragma unroll
        for (int j = 0; j < 8; ++j) {
            float f = (j < 4) ? ((const float*)&a0)[j] : ((const float*)&a1)[j - 4];
            unsigned short h = f2bf(f);
            ah[j] = (short)h;
            al[j] = (short)f2bf(f - bf2f(h));
        }
#pragma unroll
        for (int nt = 0; nt < kNT; ++nt) {
            short8v bh = whv[(ks * kNT + nt) * 64 + lane];
            short8v bl = wlv[(ks * kNT + nt) * 64 + lane];
            accH[nt] = __builtin_amdgcn_mfma_f32_16x16x32_bf16(ah, bh, accH[nt], 0, 0, 0);
            accL[nt] = __builtin_amdgcn_mfma_f32_16x16x32_bf16(ah, bl, accL[nt], 0, 0, 0);
            accL[nt] = __builtin_amdgcn_mfma_f32_16x16x32_bf16(al, bh, accL[nt], 0, 0, 0);
        }
    }

    int col0 = lane & 15;
    int rsub = (lane >> 4) * 4;
    float sq[4] = {0.f, 0.f, 0.f, 0.f};
#pragma unroll
    for (int nt = 0; nt < kNT; ++nt) {
        float bb = b[nt * 16 + col0];
#pragma unroll
        for (int r = 0; r < 4; ++r) {
            int row = r0 + rsub + r;
            float v = tanhf(accH[nt][r] + accL[nt][r] + bb);
            sq[r] = fmaf(v, v, sq[r]);
            if (row < kNItem) {
                __half h = __float2half_rn(v);
                egoh[(size_t)(kNUser + row) * kEmb + nt * 16 + col0] =
                    *(unsigned short*)&h;
            }
        }
    }
#pragma unroll
    for (int r = 0; r < 4; ++r) {
#pragma unroll
        for (int o = 1; o <= 8; o <<= 1) sq[r] += __shfl_xor(sq[r], o, 64);
        int row = r0 + rsub + r;
        if (col0 == 0 && row < kNItem) nrm[kNUser + row] = sqrtf(sq[r]);
    }
}

// ---- fallback-path item MLP (fp32 VALU, LDS-staged) ----
constexpr int kRW      = 16;   // rows per wave
constexpr int kRowsBlk = 64;   // rows per block (4 waves)
constexpr int kKc      = 32;   // K-chunk

__global__ __launch_bounds__(256, 2)
void item_ego_k(const float* __restrict__ itf, const float* __restrict__ w,
                const float* __restrict__ b, float* __restrict__ ego) {
    __shared__ float lds_a[kRowsBlk * kKc];  // 8 KB
    int t      = threadIdx.x;
    int wid    = t >> 6;
    int lane   = t & 63;
    int blk_r0 = blockIdx.x * kRowsBlk;

    float acc[kRW];
#pragma unroll
    for (int r = 0; r < kRW; ++r) acc[r] = 0.f;

    int srow = t >> 3;             // 0..31
    int scol = (t & 7) * 4;        // 0,4,..,28

    for (int kc = 0; kc < kFeat; kc += kKc) {
        __syncthreads();
        {
            const float4 z = make_float4(0.f, 0.f, 0.f, 0.f);
            int gr0 = blk_r0 + srow;
            int gr1 = gr0 + 32;
            float4 v0 = (gr0 < kNItem)
                ? *(const float4*)(itf + (size_t)gr0 * kFeat + kc + scol) : z;
            float4 v1 = (gr1 < kNItem)
                ? *(const float4*)(itf + (size_t)gr1 * kFeat + kc + scol) : z;
            *(float4*)(lds_a + srow * kKc + scol)        = v0;
            *(float4*)(lds_a + (srow + 32) * kKc + scol) = v1;
        }
        float wreg[kKc];
#pragma unroll
        for (int k = 0; k < kKc; ++k) wreg[k] = w[(kc + k) * kEmb + lane];
        __syncthreads();
#pragma unroll
        for (int r = 0; r < kRW; ++r) {
            const float4* av = (const float4*)(lds_a + (wid * kRW + r) * kKc);
#pragma unroll
            for (int q = 0; q < 8; ++q) {
                float4 a = av[q];
                acc[r] = fmaf(a.x, wreg[q * 4 + 0], acc[r]);
                acc[r] = fmaf(a.y, wreg[q * 4 + 1], acc[r]);
                acc[r] = fmaf(a.z, wreg[q * 4 + 2], acc[r]);
                acc[r] = fmaf(a.w, wreg[q * 4 + 3], acc[r]);
            }
        }
    }
    float bv = b[lane];
#pragma unroll
    for (int r = 0; r < kRW; ++r) {
        int row = blk_r0 + wid * kRW + r;
        if (row < kNItem)
            ego[(size_t)(kNUser + row) * kEmb + lane] = tanhf(acc[r] + bv);
    }
}

// ================= CSR build (bucket counting sort, no global row atomics) =================

// 256-bin bucket histogram, LDS-aggregated (150K global atomics total)
__global__ __launch_bounds__(256)
void bcnt_k(const int* __restrict__ rows, int* __restrict__ bcnt) {
    __shared__ int cnt[kNBkt];
    int t  = threadIdx.x;
    int e0 = blockIdx.x * kChunkA;
    for (int i = t; i < kNBkt; i += 256) cnt[i] = 0;
    __syncthreads();
#pragma unroll
    for (int k = 0; k < kChunkA / 256; ++k) {
        int e = e0 + k * 256 + t;
        if (e < kNnz) atomicAdd(&cnt[rows[e] / kBR], 1);
    }
    __syncthreads();
    for (int i = t; i < kNBkt; i += 256)
        if (cnt[i]) atomicAdd(&bcnt[i], cnt[i]);
}

// exclusive scan of the 256 bucket counts -> bbase; also zeroes bfill
__global__ void bscan_k(const int* __restrict__ bcnt, int* __restrict__ bbase,
                        int* __restrict__ bfill) {
    __shared__ int sd[kNBkt];
    int t = threadIdx.x;
    int v = bcnt[t];
    sd[t] = v;
    __syncthreads();
#pragma unroll
    for (int off = 1; off < kNBkt; off <<= 1) {
        int u = (t >= off) ? sd[t - off] : 0;
        __syncthreads();
        sd[t] += u;
        __syncthreads();
    }
    bbase[t] = sd[t] - v;
    if (t == kNBkt - 1) bbase[kNBkt] = kNnz;
    bfill[t] = 0;
}

// phase A: partition edges into 256 row-range buckets (LDS histogram + one
// global atomicAdd per (WG,bucket) reserving a contiguous run).
__global__ __launch_bounds__(256)
void bucket_k(const int* __restrict__ rows, const int* __restrict__ cols,
              const float* __restrict__ vals, const int* __restrict__ bbase,
              int* __restrict__ bfill, int2* __restrict__ tmp) {
    __shared__ int cnt[kNBkt];
    __shared__ int wgbase[kNBkt];
    int t  = threadIdx.x;
    int e0 = blockIdx.x * kChunkA;
    for (int i = t; i < kNBkt; i += 256) cnt[i] = 0;
    __syncthreads();
    int myb[kChunkA / 256];
    int myoff[kChunkA / 256];
#pragma unroll
    for (int k = 0; k < kChunkA / 256; ++k) {
        int e = e0 + k * 256 + t;                 // coalesced
        if (e < kNnz) {
            int b = rows[e] / kBR;                // const-divisor magic mul
            myb[k]   = b;
            myoff[k] = atomicAdd(&cnt[b], 1);     // LDS atomic
        } else {
            myb[k] = -1;
        }
    }
    __syncthreads();
    for (int i = t; i < kNBkt; i += 256)
        wgbase[i] = cnt[i] ? atomicAdd(&bfill[i], cnt[i]) : 0;
    __syncthreads();
#pragma unroll
    for (int k = 0; k < kChunkA / 256; ++k) {
        int b = myb[k];
        if (b < 0) continue;
        int e = e0 + k * 256 + t;
        int pos = bbase[b] + wgbase[b] + myoff[k];
        int rowrel = rows[e] - b * kBR;           // re-read, L2-hot
        tmp[pos] = make_int2((rowrel << 18) | cols[e], __float_as_int(vals[e]));
    }
}

// phase B: one WG per bucket. Counts its 586 rows in LDS, scans them in LDS,
// writes row_ptr coalesced, then places edges via LDS-atomic fill into the
// L2-resident csr window. Zero global atomics.
__global__ __launch_bounds__(256)
void debucket2_k(const int2* __restrict__ tmp, const int* __restrict__ bbase,
                 int* __restrict__ rp, int2* __restrict__ csr) {
    __shared__ int rcnt[kBR];
    __shared__ int rbaseL[kBR];
    __shared__ int sd[256];
    int b  = blockIdx.x;
    int t  = threadIdx.x;
    int j0 = bbase[b];
    int j1 = bbase[b + 1];
    for (int i = t; i < kBR; i += 256) rcnt[i] = 0;
    __syncthreads();
    // pass 1: row histogram within bucket
    for (int j = j0 + t; j < j1; j += 256)
        atomicAdd(&rcnt[(unsigned)tmp[j].x >> 18], 1);
    __syncthreads();
    // scan 586 row counts: thread t owns elements [3t, 3t+3)
    int base = t * 3;
    int c0 = (base     < kBR) ? rcnt[base]     : 0;
    int c1 = (base + 1 < kBR) ? rcnt[base + 1] : 0;
    int c2 = (base + 2 < kBR) ? rcnt[base + 2] : 0;
    int tsum = c0 + c1 + c2;
    sd[t] = tsum;
    __syncthreads();
#pragma unroll
    for (int off = 1; off < 256; off <<= 1) {
        int u = (t >= off) ? sd[t - off] : 0;
        __syncthreads();
        sd[t] += u;
        __syncthreads();
    }
    int g0 = j0 + sd[t] - tsum;
    if (base     < kBR) rbaseL[base]     = g0;
    if (base + 1 < kBR) rbaseL[base + 1] = g0 + c0;
    if (base + 2 < kBR) rbaseL[base + 2] = g0 + c0 + c1;
    __syncthreads();
    // row_ptr out (coalesced)
    int rbaseG = b * kBR;
    for (int i = t; i < kBR; i += 256) {
        int r = rbaseG + i;
        if (r < kN) rp[r] = rbaseL[i];
    }
    if (b == kNBkt - 1 && t == 0) rp[kN] = kNnz;
    // reset counters for fill pass
    for (int i = t; i < kBR; i += 256) rcnt[i] = 0;
    __syncthreads();
    // pass 2: place edges (tmp window is L2-hot from pass 1)
    for (int j = j0 + t; j < j1; j += 256) {
        int2 e = tmp[j];
        int rr = (unsigned)e.x >> 18;
        int pos = rbaseL[rr] + atomicAdd(&rcnt[rr], 1);
        csr[pos] = make_int2(e.x & 0x3FFFF, e.y);
    }
}

// ============ fused layer: pull-SpMM + cosine reweight ============
// R10: no fp32 ego anywhere — the cosine dot and the last-layer epilogue
// both use the fp16 egoh row (128 B read vs 256 B). acc = egoh + x1+x2+x3+x4
// composed in the last layer only.
__global__ __launch_bounds__(256)
void layer_k(const int* __restrict__ rp, const int2* __restrict__ csr,
             const unsigned short* __restrict__ egoh, const float* __restrict__ nrm,
             const unsigned short* __restrict__ xin_h,
             unsigned short* __restrict__ xout_h,
             const unsigned short* __restrict__ xh1,
             const unsigned short* __restrict__ xh2,
             float* __restrict__ acc, int last) {
    int wid  = threadIdx.x >> 6;
    int lane = threadIdx.x & 63;
    int row  = blockIdx.x * 4 + wid;
    if (row >= kN) return;
    int q   = lane >> 4;        // edge slot within a group of 4
    int sub = lane & 15;        // dim quad: dims 4*sub .. 4*sub+3
    int p0 = rp[row];
    int p1 = rp[row + 1];

    float4 s = make_float4(0.f, 0.f, 0.f, 0.f);
    for (int base = p0; base < p1; base += 16) {
        int2  e[4];
        float w[4];
#pragma unroll
        for (int g = 0; g < 4; ++g) {
            int j  = base + g * 4 + q;
            bool v = j < p1;
            e[g] = csr[v ? j : p0];          // 16-lane broadcast load, 8 B
            w[g] = v ? __int_as_float(e[g].y) : 0.f;
        }
        uint2 gv[4];
#pragma unroll
        for (int g = 0; g < 4; ++g)
            gv[g] = *(const uint2*)(xin_h + (size_t)e[g].x * kEmb + sub * 4);
#pragma unroll
        for (int g = 0; g < 4; ++g) {
            float2 f0 = __half22float2(*(const __half2*)&gv[g].x);
            float2 f1 = __half22float2(*(const __half2*)&gv[g].y);
            s.x = fmaf(w[g], f0.x, s.x);
            s.y = fmaf(w[g], f0.y, s.y);
            s.z = fmaf(w[g], f1.x, s.z);
            s.w = fmaf(w[g], f1.y, s.w);
        }
    }
    // fold the 4 edge slots
#pragma unroll
    for (int o = 16; o <= 32; o <<= 1) {
        s.x += __shfl_xor(s.x, o, 64);
        s.y += __shfl_xor(s.y, o, 64);
        s.z += __shfl_xor(s.z, o, 64);
        s.w += __shfl_xor(s.w, o, 64);
    }
    size_t idx = (size_t)row * kEmb + sub * 4;
    uint2 evu = *(const uint2*)(egoh + idx);
    float2 ea = __half22float2(*(const __half2*)&evu.x);
    float2 eb = __half22float2(*(const __half2*)&evu.y);
    float4 ev = make_float4(ea.x, ea.y, eb.x, eb.y);
    float d = s.x * ev.x + s.y * ev.y + s.z * ev.z + s.w * ev.w;
    float n = s.x * s.x + s.y * s.y + s.z * s.z + s.w * s.w;
#pragma unroll
    for (int o = 1; o <= 8; o <<= 1) {
        d += __shfl_xor(d, o, 64);
        n += __shfl_xor(n, o, 64);
    }
    float wgt = d / fmaxf(sqrtf(n) * nrm[row], kEps);
    if (q == 0) {   // one replica writes
        float4 xw = make_float4(wgt * s.x, wgt * s.y, wgt * s.z, wgt * s.w);
        if (!last) {
            __half2 o0 = __floats2half2_rn(xw.x, xw.y);
            __half2 o1 = __floats2half2_rn(xw.z, xw.w);
            uint2 st;
            st.x = *(unsigned*)&o0;
            st.y = *(unsigned*)&o1;
            *(uint2*)(xout_h + idx) = st;
        } else {
            // acc = ego + x1 + x2 + x3 + x4  (x3 == this layer's xin)
            uint2 a1 = *(const uint2*)(xh1 + idx);
            uint2 a2 = *(const uint2*)(xh2 + idx);
            uint2 a3 = *(const uint2*)(xin_h + idx);
            float2 f1a = __half22float2(*(const __half2*)&a1.x);
            float2 f1b = __half22float2(*(const __half2*)&a1.y);
            float2 f2a = __half22float2(*(const __half2*)&a2.x);
            float2 f2b = __half22float2(*(const __half2*)&a2.y);
            float2 f3a = __half22float2(*(const __half2*)&a3.x);
            float2 f3b = __half22float2(*(const __half2*)&a3.y);
            float4 out;
            out.x = ev.x + f1a.x + f2a.x + f3a.x + xw.x;
            out.y = ev.y + f1a.y + f2a.y + f3a.y + xw.y;
            out.z = ev.z + f1b.x + f2b.x + f3b.x + xw.z;
            out.w = ev.w + f1b.y + f2b.y + f3b.y + xw.w;
            *(float4*)(acc + idx) = out;
        }
    }
}

// ================= fallback (atomic) kernels =================

__global__ void norm_init_full_k(const float* __restrict__ ego, float* __restrict__ nrm,
                                 float* __restrict__ x, float* __restrict__ acc) {
    int wid  = threadIdx.x >> 6;
    int lane = threadIdx.x & 63;
    int row  = blockIdx.x * 4 + wid;
    if (row >= kN) return;
    size_t idx = (size_t)row * kEmb + lane;
    float e = ego[idx];
    x[idx]   = e;
    acc[idx] = e;
    float s = e * e;
#pragma unroll
    for (int o = 32; o >= 1; o >>= 1) s += __shfl_xor(s, o, 64);
    if (lane == 0) nrm[row] = sqrtf(s);
}

__global__ void spmm_k(const int* __restrict__ rows, const int* __restrict__ cols,
                       const float* __restrict__ vals, const float* __restrict__ x,
                       float* __restrict__ y) {
    long long t = (long long)blockIdx.x * blockDim.x + threadIdx.x;
    int e = (int)(t >> 6);
    if (e >= kNnz) return;
    int lane = threadIdx.x & 63;
    atomicAdd(y + (size_t)rows[e] * kEmb + lane, vals[e] * x[(size_t)cols[e] * kEmb + lane]);
}

__global__ void weight_k(const float* __restrict__ ego, const float* __restrict__ nrm,
                         const float* __restrict__ y, float* __restrict__ x,
                         float* __restrict__ acc) {
    int wid  = threadIdx.x >> 6;
    int lane = threadIdx.x & 63;
    int row  = blockIdx.x * 4 + wid;
    if (row >= kN) return;
    size_t idx = (size_t)row * kEmb + lane;
    float yv = y[idx];
    float ev = ego[idx];
    float d = yv * ev;
    float n = yv * yv;
#pragma unroll
    for (int o = 32; o >= 1; o >>= 1) {
        d += __shfl_xor(d, o, 64);
        n += __shfl_xor(n, o, 64);
    }
    float w  = d / fmaxf(sqrtf(n) * nrm[row], kEps);
    float xw = w * yv;
    x[idx] = xw;
    acc[idx] += xw;
}

// ================= launch =================

extern "C" void kernel_launch(void* const* d_in, const int* in_sizes, int n_in,
                              void* d_out, int out_size, void* d_ws, size_t ws_size,
                              hipStream_t stream) {
    const float* user_fea = (const float*)d_in[0];
    const float* item_fea = (const float*)d_in[1];
    const float* prompt   = (const float*)d_in[2];
    const float* mlp_w    = (const float*)d_in[3];
    const float* mlp_b    = (const float*)d_in[4];
    const int*   adj_rows = (const int*)d_in[5];
    const int*   adj_cols = (const int*)d_in[6];
    const float* adj_vals = (const float*)d_in[7];
    float* acc = (float*)d_out;   // written once, by the last layer

    const size_t NE = (size_t)kN * kEmb;  // 9.6M
    float* ws = (float*)d_ws;

    // ---- workspace layout (4-byte units); shared prefix, then CSR-path ----
    size_t off = 0;
    float* f_ps  = ws + off; off += 64;
    float* f_nrm = ws + off; off += kN;
    size_t branch0 = off;
    // CSR path: fp16 buffers (xh1 doubles as bucket tmp)
    unsigned short* f_egoh = (unsigned short*)(ws + off); off += NE / 2;
    unsigned short* f_xh1  = (unsigned short*)(ws + off); off += NE / 2;
    unsigned short* f_xh2  = (unsigned short*)(ws + off); off += NE / 2;
    unsigned short* f_xh3  = (unsigned short*)(ws + off); off += NE / 2;
    int* row_ptr = (int*)(ws + off); off += kN + 1;
    int* bcnt    = (int*)(ws + off); off += kNBkt;
    int* bbase   = (int*)(ws + off); off += kNBkt + 1;
    int* bfill   = (int*)(ws + off); off += kNBkt;
    off = (off + 3) & ~(size_t)3;                   // 16B-align W frags
    unsigned short* whi = (unsigned short*)(ws + off); off += kWElems / 2;
    unsigned short* wlo = (unsigned short*)(ws + off); off += kWElems / 2;
    off = (off + 1) & ~(size_t)1;                   // 8B-align csr
    int2* csr = (int2*)(ws + off); off += (size_t)kNnz * 2;
    const bool use_csr = ws_size >= off * 4;

    prompt_sum_k<<<1, 64, 0, stream>>>(prompt, f_ps);

    if (use_csr) {
        // init: egoh + nrm directly (no fp32 ego buffer, no norm_init pass)
        user_egoh_k<<<(kNUser + 3) / 4, 256, 0, stream>>>(user_fea, f_ps,
                                                          f_egoh, f_nrm);
        wsplit_k<<<(kWElems + 255) / 256, 256, 0, stream>>>(mlp_w, whi, wlo);
        item_ego_mfma_k<<<(kNItem + 63) / 64, 256, 0, stream>>>(item_fea, whi, wlo,
                                                                mlp_b, f_egoh, f_nrm);

        // bucket staging aliases f_xh1 (free until layer 0 output)
        int2* tmp = (int2*)f_xh1;
        // ---- build CSR via bucket counting sort (no global row atomics) ----
        hipMemsetAsync(bcnt, 0, kNBkt * sizeof(int), stream);
        bcnt_k<<<kNWGA, 256, 0, stream>>>(adj_rows, bcnt);
        bscan_k<<<1, kNBkt, 0, stream>>>(bcnt, bbase, bfill);
        bucket_k<<<kNWGA, 256, 0, stream>>>(adj_rows, adj_cols, adj_vals,
                                            bbase, bfill, tmp);
        debucket2_k<<<kNBkt, 256, 0, stream>>>(tmp, bbase, row_ptr, csr);

        // ---- 4 fused layers: egoh -> xh1 -> xh2 -> xh3 -> acc ----
        layer_k<<<(kN + 3) / 4, 256, 0, stream>>>(row_ptr, csr, f_egoh, f_nrm,
                                                  f_egoh, f_xh1, nullptr, nullptr,
                                                  acc, 0);
        layer_k<<<(kN + 3) / 4, 256, 0, stream>>>(row_ptr, csr, f_egoh, f_nrm,
                                                  f_xh1, f_xh2, nullptr, nullptr,
                                                  acc, 0);
        layer_k<<<(kN + 3) / 4, 256, 0, stream>>>(row_ptr, csr, f_egoh, f_nrm,
                                                  f_xh2, f_xh3, nullptr, nullptr,
                                                  acc, 0);
        layer_k<<<(kN + 3) / 4, 256, 0, stream>>>(row_ptr, csr, f_egoh, f_nrm,
                                                  f_xh3, nullptr, f_xh1, f_xh2,
                                                  acc, 1);
    } else {
        // ---- fallback: atomic path (fp32 buffers carved past shared prefix) ----
        float* f_ego = ws + branch0;
        float* f_x   = f_ego + NE;
        float* f_y   = f_x + NE;
        user_ego_k<<<(kNUser * kEmb + 255) / 256, 256, 0, stream>>>(user_fea, f_ps,
                                                                    f_ego);
        item_ego_k<<<(kNItem + kRowsBlk - 1) / kRowsBlk, 256, 0, stream>>>(
            item_fea, mlp_w, mlp_b, f_ego);
        norm_init_full_k<<<(kN + 3) / 4, 256, 0, stream>>>(f_ego, f_nrm, f_x, acc);
        for (int l = 0; l < 4; ++l) {
            hipMemsetAsync(f_y, 0, NE * sizeof(float), stream);
            spmm_k<<<(int)(((long long)kNnz * 64 + 255) / 256), 256, 0, stream>>>(
                adj_rows, adj_cols, adj_vals, f_x, f_y);
            weight_k<<<(kN + 3) / 4, 256, 0, stream>>>(f_ego, f_nrm, f_y, f_x, acc);
        }
    }
}